// Round 10
// baseline (3096.692 us; speedup 1.0000x reference)
//
#include <hip/hip_runtime.h>
#include <math.h>

#define H    512
#define OPS  12
#define E    112
#define NWG  128
#define NT   256

typedef unsigned long long u64;

// tagged-word regions in ws (u64 indices, after 16-float header)
#define TW_HB1   0                    // [2][512]  h1n
#define TW_HMB   1024                 // [2][512]  controller hidden
#define TW_SPEC  2048                 // [2][12*512] speculative h0n
#define TW_TOTAL (2048 + 2 * 6144)    // 14336

__device__ __forceinline__ float sigf(float x) { return 1.f / (1.f + expf(-x)); }

// JAX threefry2x32, key = PRNGKey(42) = (0,42), 20 rounds
__device__ __forceinline__ void threefry_42(unsigned x0, unsigned x1,
                                            unsigned& o0, unsigned& o1) {
  const unsigned k0 = 0u, k1 = 42u;
  const unsigned k2 = k0 ^ k1 ^ 0x1BD11BDAu;
  x0 += k0; x1 += k1;
#define TF_R(rot) { x0 += x1; x1 = (x1 << rot) | (x1 >> (32 - rot)); x1 ^= x0; }
  TF_R(13) TF_R(15) TF_R(26) TF_R(6)
  x0 += k1; x1 += k2 + 1u;
  TF_R(17) TF_R(29) TF_R(16) TF_R(24)
  x0 += k2; x1 += k0 + 2u;
  TF_R(13) TF_R(15) TF_R(26) TF_R(6)
  x0 += k0; x1 += k1 + 3u;
  TF_R(17) TF_R(29) TF_R(16) TF_R(24)
  x0 += k1; x1 += k2 + 4u;
  TF_R(13) TF_R(15) TF_R(26) TF_R(6)
  x0 += k2; x1 += k0 + 5u;
#undef TF_R
  o0 = x0; o1 = x1;
}

__device__ __forceinline__ float bits_to_gumbel(unsigned bits) {
  unsigned fb = (bits >> 9) | 0x3f800000u;
  float u = __uint_as_float(fb) - 1.0f;
  u = u + 1.17549435e-38f;
  u = fmaxf(1.17549435e-38f, u);
  return -logf(-logf(u));
}

__device__ __forceinline__ float decode_temp(const void* temp_p) {
  float tf = *(const float*)temp_p;
  float a = fabsf(tf);
  if (a > 1e-6f && a < 1e6f) return tf;
  int ti = *(const int*)temp_p;
  if (ti != 0 && ti > -1000000 && ti < 1000000) return (float)ti;
  double td = *(const double*)temp_p;
  double ad = fabs(td);
  if (ad > 1e-6 && ad < 1e6) return (float)td;
  return 1.0f;
}

// MALL-coherent tagged-word transport (tag<<32 | float bits): readiness and
// value in one system-scope transaction; no fences or cache ops needed.
__device__ __forceinline__ void tag_store(u64* p, unsigned tag, float f) {
  u64 v = ((u64)tag << 32) | (u64)__float_as_uint(f);
  __hip_atomic_store(p, v, __ATOMIC_RELAXED, __HIP_MEMORY_SCOPE_SYSTEM);
}
__device__ __forceinline__ void tag_poll2(const u64* p0, const u64* p1,
                                          unsigned tag, float& f0, float& f1) {
  u64 a = __hip_atomic_load(p0, __ATOMIC_RELAXED, __HIP_MEMORY_SCOPE_SYSTEM);
  u64 b = __hip_atomic_load(p1, __ATOMIC_RELAXED, __HIP_MEMORY_SCOPE_SYSTEM);
  while (((unsigned)(a >> 32) != tag) || ((unsigned)(b >> 32) != tag)) {
    __builtin_amdgcn_s_sleep(1);
    a = __hip_atomic_load(p0, __ATOMIC_RELAXED, __HIP_MEMORY_SCOPE_SYSTEM);
    b = __hip_atomic_load(p1, __ATOMIC_RELAXED, __HIP_MEMORY_SCOPE_SYSTEM);
  }
  f0 = __uint_as_float((unsigned)a);
  f1 = __uint_as_float((unsigned)b);
}

__global__ void k_init(u64* tw) {
  int t = blockIdx.x * blockDim.x + threadIdx.x;
  if (t < TW_TOTAL) tw[t] = 0ull;
}
__global__ void k_diag(float* out, float v) {
  if (threadIdx.x == 0 && blockIdx.x == 0) out[0] = v;
}

// ===========================================================================
__global__ void __launch_bounds__(NT)
policy_persist(const void* temp_p,
               const float* __restrict__ h0_in, const float* __restrict__ c0_in,
               const float* __restrict__ Wih0,  const float* __restrict__ Whh0,
               const float* __restrict__ bih0,  const float* __restrict__ bhh0,
               const float* __restrict__ Wih1,  const float* __restrict__ Whh1,
               const float* __restrict__ bih1,  const float* __restrict__ bhh1,
               const float* __restrict__ emb,   const float* __restrict__ cW1,
               const float* __restrict__ cb1,   const float* __restrict__ cW2,
               const float* __restrict__ cb2,
               float* __restrict__ out, float* ws) {
  __shared__ __align__(16) float h0full[H], shp1[H], hm[H];
  __shared__ __align__(16) float h0specfull[12 * H];       // 24 KB
  __shared__ float g0pre[16], g1bpre[16], g1loc[16];
  __shared__ float G1Aspec[12 * 16], c0spec[12 * 4];
  __shared__ float ewloc[12 * 16], b0loc[16], b1loc[16];
  __shared__ float gum[E * OPS];
  __shared__ float w1s[512 * 5];          // W1[i] slice, stride-5 padded
  __shared__ float w2s[512 * 13];         // W2[i] slice, stride-13 padded
  __shared__ float c0loc[4], c1loc[4];
  __shared__ float spart[4][4];
  __shared__ int s_act;

  const int tid = threadIdx.x;
  const int bid = blockIdx.x;
  const int j0  = bid * 4;                       // owned h-columns
  const int cb  = (bid & 7) * 16 + (bid >> 3);   // XCD-grouped HM col-block
  const float invt = 1.f / decode_temp(temp_p);

  u64* HB1  = (u64*)(ws + 16) + TW_HB1;
  u64* HMB  = (u64*)(ws + 16) + TW_HMB;
  u64* SPEC = (u64*)(ws + 16) + TW_SPEC;

  // ---------------- setup (all WG-local) -----------------------------------
  for (int p = tid; p < E * OPS; p += NT) {
    unsigned y0, y1;
    threefry_42(0u, (unsigned)p, y0, y1);
    gum[p] = bits_to_gumbel(y0 ^ y1);
  }
  for (int j = tid; j < H; j += NT) {
    h0full[j] = h0_in[j];
    shp1[j]   = h0_in[H + j];
  }
  if (tid < 192) {
    int a = tid / 16, ridx = tid % 16;
    int g = ridx >> 2, dj = ridx & 3;
    int row = g * H + j0 + dj;
    const float* er = emb + a * H;
    const float* wr = Wih0 + (size_t)row * H;
    float acc = 0.f;
    for (int k = 0; k < H; k += 4) {
      float4 e4 = *(const float4*)(er + k);
      float4 w4 = *(const float4*)(wr + k);
      acc += e4.x * w4.x + e4.y * w4.y + e4.z * w4.z + e4.w * w4.w;
    }
    ewloc[tid] = acc;
  }
  if (tid < 16) {
    int g = tid >> 2, dj = tid & 3;
    int row = g * H + j0 + dj;
    b0loc[tid] = bih0[row] + bhh0[row];
    b1loc[tid] = bih1[row] + bhh1[row];
  }
  if (tid < 4) {
    c0loc[tid] = c0_in[j0 + tid];
    c1loc[tid] = c0_in[H + j0 + tid];
  }
  __syncthreads();

  // G-pre(0) combined pass (identical to verified round-9 shadow math)
  {
    int rowidx = tid >> 3, lane = tid & 7;
    int cell = rowidx >> 4, ridx = rowidx & 15;
    int g = ridx >> 2, dj = ridx & 3;
    int row = g * H + j0 + dj;
    const float* wr = (cell ? Whh1 : Whh0) + (size_t)row * H + lane * 64;
    const float* hv = (cell ? shp1 : h0full) + lane * 64;
    float acc = 0.f;
#pragma unroll
    for (int k = 0; k < 64; k += 4) {
      float4 w4 = *(const float4*)(wr + k);
      acc += w4.x * hv[k] + w4.y * hv[k + 1] + w4.z * hv[k + 2] + w4.w * hv[k + 3];
    }
    acc += __shfl_xor(acc, 1);
    acc += __shfl_xor(acc, 2);
    acc += __shfl_xor(acc, 4);
    if (lane == 0) {
      if (cell == 0) g0pre[ridx] = acc + b0loc[ridx];
      else           g1bpre[ridx] = acc;
    }
    // W1[0] prefetch (stride-5 LDS)
    const float* wb = cW1 + (size_t)cb * 4;
    float4 r0 = *(const float4*)(wb + (size_t)tid * H);
    float4 r1 = *(const float4*)(wb + (size_t)(tid + 256) * H);
    int k0 = tid * 5, k1 = (tid + 256) * 5;
    w1s[k0] = r0.x; w1s[k0 + 1] = r0.y; w1s[k0 + 2] = r0.z; w1s[k0 + 3] = r0.w;
    w1s[k1] = r1.x; w1s[k1 + 1] = r1.y; w1s[k1 + 2] = r1.z; w1s[k1 + 3] = r1.w;
  }
  __syncthreads();

  // -------- prologue: PW0(0) (no EW), h0n(0) broadcast, G1A(0) -------------
  if (tid < 4) {
    float gi = g0pre[tid];
    float gf = g0pre[4 + tid];
    float gg = g0pre[8 + tid];
    float go = g0pre[12 + tid];
    float cn = sigf(gf) * c0loc[tid] + sigf(gi) * tanhf(gg);
    c0loc[tid] = cn;
    tag_store(&SPEC[j0 + tid], 1u, sigf(go) * tanhf(cn));   // parity0, slot a=0
  }
  {
    int t2 = tid * 2;
    tag_poll2(&SPEC[t2], &SPEC[t2 + 1], 1u, h0full[t2], h0full[t2 + 1]);
  }
  __syncthreads();
  {
    int ridx = tid >> 4, lane = tid & 15;
    int g = ridx >> 2, dj = ridx & 3;
    int row = g * H + j0 + dj;
    const float* wr = Wih1 + (size_t)row * H + lane * 32;
    const float* hv = h0full + lane * 32;
    float acc = 0.f;
#pragma unroll
    for (int k = 0; k < 32; k += 4) {
      float4 w4 = *(const float4*)(wr + k);
      acc += w4.x * hv[k] + w4.y * hv[k + 1] + w4.z * hv[k + 2] + w4.w * hv[k + 3];
    }
    acc += __shfl_xor(acc, 1);
    acc += __shfl_xor(acc, 2);
    acc += __shfl_xor(acc, 4);
    acc += __shfl_xor(acc, 8);
    if (lane == 0) G1Aspec[ridx] = acc;                     // slot a=0
  }
  __syncthreads();

#pragma unroll 1
  for (int i = 0; i < E; ++i) {
    const int p = i & 1;
    const unsigned tg = (unsigned)(i + 1);
    int a = 0;

    // ---- chain head: poll HM(i-1), sample, select -------------------------
    if (i > 0) {
      const int q = (i - 1) & 1;
      int t2 = tid * 2;
      tag_poll2(&HMB[q * 512 + t2], &HMB[q * 512 + t2 + 1], (unsigned)i,
                hm[t2], hm[t2 + 1]);
      __syncthreads();
      if (tid < 64) {
        float lg[OPS];
#pragma unroll
        for (int o = 0; o < OPS; ++o) lg[o] = 0.f;
#pragma unroll
        for (int jj = 0; jj < 8; ++jj) {
          int j = jj * 64 + tid;
          float hmv = hm[j];
          const float* w2r = &w2s[j * 13];
#pragma unroll
          for (int o = 0; o < OPS; ++o) lg[o] += hmv * w2r[o];
        }
#pragma unroll
        for (int s = 1; s < 64; s <<= 1) {
#pragma unroll
          for (int o = 0; o < OPS; ++o) lg[o] += __shfl_xor(lg[o], s);
        }
#pragma unroll
        for (int o = 0; o < OPS; ++o) lg[o] = (lg[o] + cb2[(i - 1) * OPS + o]) * invt;
        float mx = lg[0];
#pragma unroll
        for (int o = 1; o < OPS; ++o) mx = fmaxf(mx, lg[o]);
        float se = 0.f;
#pragma unroll
        for (int o = 0; o < OPS; ++o) se += expf(lg[o] - mx);
        float logZ = mx + logf(se);
        float best = -1e30f; int act = 0;
#pragma unroll
        for (int o = 0; o < OPS; ++o) {
          float v = lg[o] + gum[(i - 1) * OPS + o];
          if (v > best) { best = v; act = o; }
        }
        if (tid == 0) {
          s_act = act;
          if (bid == 0) {
            float lp = lg[act] - logZ;
            float ent = 0.f;
            for (int o = 0; o < OPS; ++o) {
              float l2 = lg[o] - logZ;
              ent -= expf(l2) * l2;
            }
            out[i - 1]         = (float)act;
            out[E + i - 1]     = lp;
            out[2 * E + i - 1] = ent;
          }
        }
      }
      __syncthreads();
      a = s_act;
      // select: commit PW0(i) results for action a (all local)
      if (tid < 4) c0loc[tid] = c0spec[a * 4 + tid];
      for (int j = tid; j < H; j += NT) h0full[j] = h0specfull[a * 512 + j];
      __syncthreads();
    }

    // ---- PW1 (wave 0, local): G1 = G1Aspec[a] + G1Bpre + B1 ---------------
    if (tid < 16) g1loc[tid] = G1Aspec[a * 16 + tid] + g1bpre[tid] + b1loc[tid];
    if (tid < 4) {
      float gi = g1loc[tid];
      float gf = g1loc[4 + tid];
      float gg = g1loc[8 + tid];
      float go = g1loc[12 + tid];
      float cn = sigf(gf) * c1loc[tid] + sigf(gi) * tanhf(gg);
      c1loc[tid] = cn;
      tag_store(&HB1[p * 512 + j0 + tid], tg, sigf(go) * tanhf(cn));
    }

    // ---- shadow-1: G0pre(i+1) = Whh0@h0n(i) + B0; W2[i] -> w2s -----------
    if (tid < 128) {
      int ridx = tid >> 3, lane = tid & 7;
      int g = ridx >> 2, dj = ridx & 3;
      int row = g * H + j0 + dj;
      const float* wr = Whh0 + (size_t)row * H + lane * 64;
      const float* hv = h0full + lane * 64;
      float acc = 0.f;
#pragma unroll
      for (int k = 0; k < 64; k += 4) {
        float4 w4 = *(const float4*)(wr + k);
        acc += w4.x * hv[k] + w4.y * hv[k + 1] + w4.z * hv[k + 2] + w4.w * hv[k + 3];
      }
      acc += __shfl_xor(acc, 1);
      acc += __shfl_xor(acc, 2);
      acc += __shfl_xor(acc, 4);
      if (lane == 0) g0pre[ridx] = acc + b0loc[ridx];
    }
    {
      const float* wsrc = cW2 + (size_t)i * H * OPS;
#pragma unroll
      for (int r = 0; r < 6; ++r) {
        int q = tid + 256 * r;
        float4 v = *(const float4*)(wsrc + 4 * q);
        int f = 4 * q;
        w2s[(f / 12) * 13 + (f % 12)]             = v.x;
        w2s[((f + 1) / 12) * 13 + ((f + 1) % 12)] = v.y;
        w2s[((f + 2) / 12) * 13 + ((f + 2) % 12)] = v.z;
        w2s[((f + 3) / 12) * 13 + ((f + 3) % 12)] = v.w;
      }
    }

    // ---- poll h1n(i) full -------------------------------------------------
    {
      int t2 = tid * 2;
      tag_poll2(&HB1[p * 512 + t2], &HB1[p * 512 + t2 + 1], tg,
                shp1[t2], shp1[t2 + 1]);
    }
    __syncthreads();

    // ---- phase C: HM own 4 cols from LDS W1 ------------------------------
    {
      int wv = tid >> 6, ln = tid & 63;
      int jl = ln & 3, ks = ln >> 2;
      int kbase = wv * 128 + ks * 8;
      float acc = 0.f;
#pragma unroll
      for (int t = 0; t < 8; ++t) {
        int k = kbase + t;
        acc += shp1[k] * w1s[k * 5 + jl];
      }
      acc += __shfl_xor(acc, 4);
      acc += __shfl_xor(acc, 8);
      acc += __shfl_xor(acc, 16);
      acc += __shfl_xor(acc, 32);
      if (ln < 4) spart[wv][ln] = acc;
    }
    __syncthreads();
    if (tid < 4) {
      float s = spart[0][tid] + spart[1][tid] + spart[2][tid] + spart[3][tid];
      s += cb1[(size_t)i * H + cb * 4 + tid];
      tag_store(&HMB[p * 512 + cb * 4 + tid], tg, fmaxf(s, 0.f));
    }

    // ---- shadow-2: spec for step i+1 -------------------------------------
    if (i + 1 < E) {
      const int pn = (i + 1) & 1;
      const unsigned tgn = (unsigned)(i + 2);
      // W1[i+1] loads issued early (latency hidden under spec work)
      const float* wb = cW1 + (size_t)(i + 1) * H * H + (size_t)cb * 4;
      float4 r0 = *(const float4*)(wb + (size_t)tid * H);
      float4 r1 = *(const float4*)(wb + (size_t)(tid + 256) * H);
      // G1Bpre(i+1) = Whh1 @ h1n(i)
      if (tid < 128) {
        int ridx = tid >> 3, lane = tid & 7;
        int g = ridx >> 2, dj = ridx & 3;
        int row = g * H + j0 + dj;
        const float* wr = Whh1 + (size_t)row * H + lane * 64;
        const float* hv = shp1 + lane * 64;
        float acc = 0.f;
#pragma unroll
        for (int k = 0; k < 64; k += 4) {
          float4 w4 = *(const float4*)(wr + k);
          acc += w4.x * hv[k] + w4.y * hv[k + 1] + w4.z * hv[k + 2] + w4.w * hv[k + 3];
        }
        acc += __shfl_xor(acc, 1);
        acc += __shfl_xor(acc, 2);
        acc += __shfl_xor(acc, 4);
        if (lane == 0) g1bpre[ridx] = acc;
      }
      // PW0-spec for all 12 actions (own 4 columns each)
      if (tid < 48) {
        int aa = tid >> 2, col = tid & 3;
        float gi = g0pre[col]      + ewloc[aa * 16 + col];
        float gf = g0pre[4 + col]  + ewloc[aa * 16 + 4 + col];
        float gg = g0pre[8 + col]  + ewloc[aa * 16 + 8 + col];
        float go = g0pre[12 + col] + ewloc[aa * 16 + 12 + col];
        float cn = sigf(gf) * c0loc[col] + sigf(gi) * tanhf(gg);
        c0spec[aa * 4 + col] = cn;
        tag_store(&SPEC[pn * 6144 + aa * 512 + j0 + col], tgn,
                  sigf(go) * tanhf(cn));
      }
      // w1s write (after C's reads, separated by the spart barrier)
      {
        int k0 = tid * 5, k1 = (tid + 256) * 5;
        w1s[k0] = r0.x; w1s[k0 + 1] = r0.y; w1s[k0 + 2] = r0.z; w1s[k0 + 3] = r0.w;
        w1s[k1] = r1.x; w1s[k1 + 1] = r1.y; w1s[k1 + 2] = r1.z; w1s[k1 + 3] = r1.w;
      }
      // batched poll of all 12 speculative h0n vectors (24 words/thread)
      {
        const u64* sp = &SPEC[pn * 6144];
        const int base = tid * 24;
        u64 v[24];
        bool ok;
        do {
          ok = true;
#pragma unroll
          for (int r = 0; r < 24; ++r)
            v[r] = __hip_atomic_load(&sp[base + r], __ATOMIC_RELAXED,
                                     __HIP_MEMORY_SCOPE_SYSTEM);
#pragma unroll
          for (int r = 0; r < 24; ++r)
            if ((unsigned)(v[r] >> 32) != tgn) ok = false;
          if (!ok) __builtin_amdgcn_s_sleep(1);
        } while (!ok);
#pragma unroll
        for (int r = 0; r < 24; ++r)
          h0specfull[base + r] = __uint_as_float((unsigned)v[r]);
      }
      __syncthreads();
      // batched G1A-spec: own 16 rows of Wih1 (regs) x 12 actions
      {
        int ridx = tid >> 4, lane = tid & 15;
        int g = ridx >> 2, dj = ridx & 3;
        int row = g * H + j0 + dj;
        const float* wr = Wih1 + (size_t)row * H + lane * 32;
        float4 w0 = *(const float4*)(wr);
        float4 w1 = *(const float4*)(wr + 4);
        float4 w2 = *(const float4*)(wr + 8);
        float4 w3 = *(const float4*)(wr + 12);
        float4 w4 = *(const float4*)(wr + 16);
        float4 w5 = *(const float4*)(wr + 20);
        float4 w6 = *(const float4*)(wr + 24);
        float4 w7 = *(const float4*)(wr + 28);
#pragma unroll 1
        for (int aa = 0; aa < 12; ++aa) {
          const float* hv = &h0specfull[aa * 512 + lane * 32];
          float acc = 0.f;
          acc += w0.x * hv[0]  + w0.y * hv[1]  + w0.z * hv[2]  + w0.w * hv[3];
          acc += w1.x * hv[4]  + w1.y * hv[5]  + w1.z * hv[6]  + w1.w * hv[7];
          acc += w2.x * hv[8]  + w2.y * hv[9]  + w2.z * hv[10] + w2.w * hv[11];
          acc += w3.x * hv[12] + w3.y * hv[13] + w3.z * hv[14] + w3.w * hv[15];
          acc += w4.x * hv[16] + w4.y * hv[17] + w4.z * hv[18] + w4.w * hv[19];
          acc += w5.x * hv[20] + w5.y * hv[21] + w5.z * hv[22] + w5.w * hv[23];
          acc += w6.x * hv[24] + w6.y * hv[25] + w6.z * hv[26] + w6.w * hv[27];
          acc += w7.x * hv[28] + w7.y * hv[29] + w7.z * hv[30] + w7.w * hv[31];
          acc += __shfl_xor(acc, 1);
          acc += __shfl_xor(acc, 2);
          acc += __shfl_xor(acc, 4);
          acc += __shfl_xor(acc, 8);
          if (lane == 0) G1Aspec[aa * 16 + ridx] = acc;
        }
      }
    }
    __syncthreads();
  }

  // ---- final sampling (step E-1); w2s = W2[E-1] ---------------------------
  if (bid == 0) {
    const int q = (E - 1) & 1;
    int t2 = tid * 2;
    tag_poll2(&HMB[q * 512 + t2], &HMB[q * 512 + t2 + 1], (unsigned)E,
              hm[t2], hm[t2 + 1]);
    __syncthreads();
    if (tid < 64) {
      float lg[OPS];
#pragma unroll
      for (int o = 0; o < OPS; ++o) lg[o] = 0.f;
#pragma unroll
      for (int jj = 0; jj < 8; ++jj) {
        int j = jj * 64 + tid;
        float hmv = hm[j];
        const float* w2r = &w2s[j * 13];
#pragma unroll
        for (int o = 0; o < OPS; ++o) lg[o] += hmv * w2r[o];
      }
#pragma unroll
      for (int s = 1; s < 64; s <<= 1) {
#pragma unroll
        for (int o = 0; o < OPS; ++o) lg[o] += __shfl_xor(lg[o], s);
      }
#pragma unroll
      for (int o = 0; o < OPS; ++o) lg[o] = (lg[o] + cb2[(E - 1) * OPS + o]) * invt;
      float mx = lg[0];
#pragma unroll
      for (int o = 1; o < OPS; ++o) mx = fmaxf(mx, lg[o]);
      float se = 0.f;
#pragma unroll
      for (int o = 0; o < OPS; ++o) se += expf(lg[o] - mx);
      float logZ = mx + logf(se);
      float best = -1e30f; int act = 0;
#pragma unroll
      for (int o = 0; o < OPS; ++o) {
        float v = lg[o] + gum[(E - 1) * OPS + o];
        if (v > best) { best = v; act = o; }
      }
      if (tid == 0) {
        float lp = lg[act] - logZ;
        float ent = 0.f;
        for (int o = 0; o < OPS; ++o) {
          float l2 = lg[o] - logZ;
          ent -= expf(l2) * l2;
        }
        out[E - 1]     = (float)act;
        out[2 * E - 1] = lp;
        out[3 * E - 1] = ent;
      }
    }
  }
}

// ===========================================================================
extern "C" void kernel_launch(void* const* d_in, const int* in_sizes, int n_in,
                              void* d_out, int out_size, void* d_ws, size_t ws_size,
                              hipStream_t stream) {
  (void)out_size; (void)ws_size;
  float* out = (float*)d_out;
  float* ws  = (float*)d_ws;

  (void)hipGetLastError();

  static const long long expect[16] = {
      1, 1024, 1024, 1048576, 1048576, 2048, 2048,
      1048576, 1048576, 2048, 2048, 6144,
      29360128, 57344, 688128, 1344 };
  int bad = -1;
  if (n_in != 16) bad = 99;
  else {
    for (int i = 0; i < 16; ++i)
      if ((long long)in_sizes[i] != expect[i]) { bad = i; break; }
  }

  k_init<<<56, 256, 0, stream>>>((u64*)(ws + 16));
  if (bad >= 0) {
    k_diag<<<1, 64, 0, stream>>>(out, 80000.0f + (float)bad);
    return;
  }

  policy_persist<<<NWG, NT, 0, stream>>>(
      d_in[0],
      (const float*)d_in[1],  (const float*)d_in[2],
      (const float*)d_in[3],  (const float*)d_in[4],
      (const float*)d_in[5],  (const float*)d_in[6],
      (const float*)d_in[7],  (const float*)d_in[8],
      (const float*)d_in[9],  (const float*)d_in[10],
      (const float*)d_in[11], (const float*)d_in[12],
      (const float*)d_in[13], (const float*)d_in[14],
      (const float*)d_in[15],
      out, ws);

  hipError_t e = hipGetLastError();
  if (e != hipSuccess) {
    k_diag<<<1, 64, 0, stream>>>(out, 90000.0f + (float)(int)e);
  }
}

// Round 11
// 2233.766 us; speedup vs baseline: 1.3863x; 1.3863x over previous
//
#include <hip/hip_runtime.h>
#include <math.h>

#define H    512
#define OPS  12
#define E    112
#define NWG  32
#define NT   256
#define JW   16            // h-columns owned per WG

typedef unsigned long long u64;

// ws layout: 16-float header | 3072 u64 tagged words | W1T (optional, 112 MB)
#define TW_HB0   0                    // [2][512] h0n
#define TW_HB1   1024                 // [2][512] h1n
#define TW_HMB   2048                 // [2][512] controller hidden
#define TW_TOTAL 3072
#define WS_W1T_F (16 + 2 * TW_TOTAL)  // float offset of W1T region (6160)

__device__ __forceinline__ float sigf(float x) { return 1.f / (1.f + expf(-x)); }

// JAX threefry2x32, key = PRNGKey(42) = (0,42), 20 rounds
__device__ __forceinline__ void threefry_42(unsigned x0, unsigned x1,
                                            unsigned& o0, unsigned& o1) {
  const unsigned k0 = 0u, k1 = 42u;
  const unsigned k2 = k0 ^ k1 ^ 0x1BD11BDAu;
  x0 += k0; x1 += k1;
#define TF_R(rot) { x0 += x1; x1 = (x1 << rot) | (x1 >> (32 - rot)); x1 ^= x0; }
  TF_R(13) TF_R(15) TF_R(26) TF_R(6)
  x0 += k1; x1 += k2 + 1u;
  TF_R(17) TF_R(29) TF_R(16) TF_R(24)
  x0 += k2; x1 += k0 + 2u;
  TF_R(13) TF_R(15) TF_R(26) TF_R(6)
  x0 += k0; x1 += k1 + 3u;
  TF_R(17) TF_R(29) TF_R(16) TF_R(24)
  x0 += k1; x1 += k2 + 4u;
  TF_R(13) TF_R(15) TF_R(26) TF_R(6)
  x0 += k2; x1 += k0 + 5u;
#undef TF_R
  o0 = x0; o1 = x1;
}

__device__ __forceinline__ float bits_to_gumbel(unsigned bits) {
  unsigned fb = (bits >> 9) | 0x3f800000u;
  float u = __uint_as_float(fb) - 1.0f;
  u = u + 1.17549435e-38f;
  u = fmaxf(1.17549435e-38f, u);
  return -logf(-logf(u));
}

__device__ __forceinline__ float decode_temp(const void* temp_p) {
  float tf = *(const float*)temp_p;
  float a = fabsf(tf);
  if (a > 1e-6f && a < 1e6f) return tf;
  int ti = *(const int*)temp_p;
  if (ti != 0 && ti > -1000000 && ti < 1000000) return (float)ti;
  double td = *(const double*)temp_p;
  double ad = fabs(td);
  if (ad > 1e-6 && ad < 1e6) return (float)td;
  return 1.0f;
}

// MALL-coherent tagged-word transport (tag<<32 | float bits)
__device__ __forceinline__ void tag_store(u64* p, unsigned tag, float f) {
  u64 v = ((u64)tag << 32) | (u64)__float_as_uint(f);
  __hip_atomic_store(p, v, __ATOMIC_RELAXED, __HIP_MEMORY_SCOPE_SYSTEM);
}
__device__ __forceinline__ void tag_poll2(const u64* p0, const u64* p1,
                                          unsigned tag, float& f0, float& f1) {
  u64 a = __hip_atomic_load(p0, __ATOMIC_RELAXED, __HIP_MEMORY_SCOPE_SYSTEM);
  u64 b = __hip_atomic_load(p1, __ATOMIC_RELAXED, __HIP_MEMORY_SCOPE_SYSTEM);
  while (((unsigned)(a >> 32) != tag) || ((unsigned)(b >> 32) != tag)) {
    __builtin_amdgcn_s_sleep(1);
    a = __hip_atomic_load(p0, __ATOMIC_RELAXED, __HIP_MEMORY_SCOPE_SYSTEM);
    b = __hip_atomic_load(p1, __ATOMIC_RELAXED, __HIP_MEMORY_SCOPE_SYSTEM);
  }
  f0 = __uint_as_float((unsigned)a);
  f1 = __uint_as_float((unsigned)b);
}

__global__ void k_init(u64* tw) {
  int t = blockIdx.x * blockDim.x + threadIdx.x;
  if (t < TW_TOTAL) tw[t] = 0ull;
}
__global__ void k_diag(float* out, float v) {
  if (threadIdx.x == 0 && blockIdx.x == 0) out[0] = v;
}

// transpose cW1 -> W1T[((i*32+b)*512 + k)*16 + jc] = cW1[i][k][b*16+jc]
__global__ void __launch_bounds__(NT)
k_w1t(const float* __restrict__ cW1, float* __restrict__ w1t) {
  int t = blockIdx.x * NT + threadIdx.x;            // float4 index
  size_t e0 = (size_t)t * 4;
  int i = (int)(e0 >> 18);                           // /262144
  int rem = (int)(e0 & 262143);
  int k = rem >> 9, j = rem & 511;
  int b = j >> 4, jc = j & 15;
  float4 v = *(const float4*)(cW1 + e0);
  size_t dst = (((size_t)(i * 32 + b) * 512 + k) << 4) + jc;
  *(float4*)(w1t + dst) = v;
}

// ===========================================================================
__global__ void __launch_bounds__(NT)
policy_persist(const void* temp_p,
               const float* __restrict__ h0_in, const float* __restrict__ c0_in,
               const float* __restrict__ Wih0,  const float* __restrict__ Whh0,
               const float* __restrict__ bih0,  const float* __restrict__ bhh0,
               const float* __restrict__ Wih1,  const float* __restrict__ Whh1,
               const float* __restrict__ bih1,  const float* __restrict__ bhh1,
               const float* __restrict__ emb,   const float* __restrict__ cW1,
               const float* __restrict__ cb1,   const float* __restrict__ cW2,
               const float* __restrict__ cb2,
               float* __restrict__ out, float* ws, int use_w1t) {
  __shared__ __align__(16) float h0full[H], shp1[H], hm[H];
  __shared__ float g0pre[64], g1bpre[64], g1loc[64];
  __shared__ float ewloc[12 * 64], b0loc[64], b1loc[64];
  __shared__ float gum[E * OPS];
  __shared__ __align__(16) float w1s[512 * 17];     // W1[i] 16-col slice, pad 17
  __shared__ float w2s[512 * 13];                   // W2[i], pad 13
  __shared__ float c0loc[JW], c1loc[JW];
  __shared__ float spart[4][4];
  __shared__ int s_act;

  const int tid = threadIdx.x;
  const int bid = blockIdx.x;
  const int j0  = bid * JW;
  const float invt = 1.f / decode_temp(temp_p);

  u64* HB0 = (u64*)(ws + 16) + TW_HB0;
  u64* HB1 = (u64*)(ws + 16) + TW_HB1;
  u64* HMB = (u64*)(ws + 16) + TW_HMB;
  const float* W1T = ws + WS_W1T_F;

  // ---------------- setup (all WG-local) -----------------------------------
  for (int p = tid; p < E * OPS; p += NT) {
    unsigned y0, y1;
    threefry_42(0u, (unsigned)p, y0, y1);
    gum[p] = bits_to_gumbel(y0 ^ y1);
  }
  for (int j = tid; j < H; j += NT) {
    h0full[j] = h0_in[j];
    shp1[j]   = h0_in[H + j];
  }
  for (int e = tid; e < 12 * 64; e += NT) {         // ewloc[a*64 + ridx]
    int a = e >> 6, ridx = e & 63;
    int g = ridx >> 4, dj = ridx & 15;
    int row = g * H + j0 + dj;
    const float* er = emb + a * H;
    const float* wr = Wih0 + (size_t)row * H;
    float acc = 0.f;
    for (int k = 0; k < H; k += 4) {
      float4 e4 = *(const float4*)(er + k);
      float4 w4 = *(const float4*)(wr + k);
      acc += e4.x * w4.x + e4.y * w4.y + e4.z * w4.z + e4.w * w4.w;
    }
    ewloc[e] = acc;
  }
  if (tid < 64) {
    int g = tid >> 4, dj = tid & 15;
    int row = g * H + j0 + dj;
    b0loc[tid] = bih0[row] + bhh0[row];
    b1loc[tid] = bih1[row] + bhh1[row];
  }
  if (tid < JW) {
    c0loc[tid] = c0_in[j0 + tid];
    c1loc[tid] = c0_in[H + j0 + tid];
  }
  __syncthreads();

  // G-pre(0): g0pre = Whh0@h + B0, g1bpre = Whh1@h (own 64+64 rows, 8 lanes)
#pragma unroll 1
  for (int it = 0; it < 4; ++it) {
    int task = it * NT + tid;
    int rowidx = task >> 3, lane = task & 7;
    int cell = rowidx >> 6, ridx = rowidx & 63;
    int g = ridx >> 4, dj = ridx & 15;
    int row = g * H + j0 + dj;
    const float* wr = (cell ? Whh1 : Whh0) + (size_t)row * H + lane * 64;
    const float* hv = (cell ? shp1 : h0full) + lane * 64;
    float acc = 0.f;
#pragma unroll
    for (int k = 0; k < 64; k += 4) {
      float4 w4 = *(const float4*)(wr + k);
      acc += w4.x * hv[k] + w4.y * hv[k + 1] + w4.z * hv[k + 2] + w4.w * hv[k + 3];
    }
    acc += __shfl_xor(acc, 1);
    acc += __shfl_xor(acc, 2);
    acc += __shfl_xor(acc, 4);
    if (lane == 0) {
      if (cell == 0) g0pre[ridx] = acc + b0loc[ridx];
      else           g1bpre[ridx] = acc;
    }
  }
  // W1[0] -> w1s
  if (use_w1t) {
    const float* wt = W1T + ((size_t)bid * 512 << 4);
#pragma unroll
    for (int r = 0; r < 8; ++r) {
      int q = r * NT + tid;
      float4 v = *(const float4*)(wt + (size_t)q * 4);
      int k = q >> 2, jc0 = (q & 3) * 4;
      float* d = &w1s[k * 17 + jc0];
      d[0] = v.x; d[1] = v.y; d[2] = v.z; d[3] = v.w;
    }
  } else {
#pragma unroll
    for (int r = 0; r < 8; ++r) {
      int q = r * NT + tid;
      int k = q >> 2, jc0 = (q & 3) * 4;
      float4 v = *(const float4*)(cW1 + (size_t)k * H + j0 + jc0);
      float* d = &w1s[k * 17 + jc0];
      d[0] = v.x; d[1] = v.y; d[2] = v.z; d[3] = v.w;
    }
  }
  __syncthreads();

#pragma unroll 1
  for (int i = 0; i < E; ++i) {
    const int p = i & 1;
    const unsigned tg = (unsigned)(i + 1);
    int a = -1;

    // ---- 1: sample step i-1 (poll HM tag i; w2s = W2[i-1]) ----------------
    if (i > 0) {
      const int q = (i - 1) & 1;
      int t2 = tid * 2;
      tag_poll2(&HMB[q * 512 + t2], &HMB[q * 512 + t2 + 1], (unsigned)i,
                hm[t2], hm[t2 + 1]);
      __syncthreads();
      if (tid < 64) {
        float lg[OPS];
#pragma unroll
        for (int o = 0; o < OPS; ++o) lg[o] = 0.f;
#pragma unroll
        for (int jj = 0; jj < 8; ++jj) {
          int j = jj * 64 + tid;
          float hmv = hm[j];
          const float* w2r = &w2s[j * 13];
#pragma unroll
          for (int o = 0; o < OPS; ++o) lg[o] += hmv * w2r[o];
        }
#pragma unroll
        for (int s = 1; s < 64; s <<= 1) {
#pragma unroll
          for (int o = 0; o < OPS; ++o) lg[o] += __shfl_xor(lg[o], s);
        }
#pragma unroll
        for (int o = 0; o < OPS; ++o) lg[o] = (lg[o] + cb2[(i - 1) * OPS + o]) * invt;
        float mx = lg[0];
#pragma unroll
        for (int o = 1; o < OPS; ++o) mx = fmaxf(mx, lg[o]);
        float se = 0.f;
#pragma unroll
        for (int o = 0; o < OPS; ++o) se += expf(lg[o] - mx);
        float logZ = mx + logf(se);
        float best = -1e30f; int act = 0;
#pragma unroll
        for (int o = 0; o < OPS; ++o) {
          float v = lg[o] + gum[(i - 1) * OPS + o];
          if (v > best) { best = v; act = o; }
        }
        if (tid == 0) {
          s_act = act;
          if (bid == 0) {
            float lp = lg[act] - logZ;
            float ent = 0.f;
            for (int o = 0; o < OPS; ++o) {
              float l2 = lg[o] - logZ;
              ent -= expf(l2) * l2;
            }
            out[i - 1]         = (float)act;
            out[E + i - 1]     = lp;
            out[2 * E + i - 1] = ent;
          }
        }
      }
      __syncthreads();
      a = s_act;
    }

    // ---- 2: PW0 (own 16 cols) -> tagged h0n store -------------------------
    if (tid < JW) {
      float gi = g0pre[tid];
      float gf = g0pre[16 + tid];
      float gg = g0pre[32 + tid];
      float go = g0pre[48 + tid];
      if (a >= 0) {
        gi += ewloc[a * 64 + tid];
        gf += ewloc[a * 64 + 16 + tid];
        gg += ewloc[a * 64 + 32 + tid];
        go += ewloc[a * 64 + 48 + tid];
      }
      float cn = sigf(gf) * c0loc[tid] + sigf(gi) * tanhf(gg);
      c0loc[tid] = cn;
      tag_store(&HB0[p * 512 + j0 + tid], tg, sigf(go) * tanhf(cn));
    }

    // ---- 3: poll full h0n -------------------------------------------------
    {
      int t2 = tid * 2;
      tag_poll2(&HB0[p * 512 + t2], &HB0[p * 512 + t2 + 1], tg,
                h0full[t2], h0full[t2 + 1]);
    }
    __syncthreads();

    // ---- 4: G1 = Wih1@h0n + G1Bpre + B1 (own 64 rows, 16 lanes/row) -------
#pragma unroll 1
    for (int it = 0; it < 4; ++it) {
      int task = it * NT + tid;
      int ridx = task >> 4, lane = task & 15;
      int g = ridx >> 4, dj = ridx & 15;
      int row = g * H + j0 + dj;
      const float* wr = Wih1 + (size_t)row * H + lane * 32;
      const float* hv = h0full + lane * 32;
      float acc = 0.f;
#pragma unroll
      for (int k = 0; k < 32; k += 4) {
        float4 w4 = *(const float4*)(wr + k);
        acc += w4.x * hv[k] + w4.y * hv[k + 1] + w4.z * hv[k + 2] + w4.w * hv[k + 3];
      }
      acc += __shfl_xor(acc, 1);
      acc += __shfl_xor(acc, 2);
      acc += __shfl_xor(acc, 4);
      acc += __shfl_xor(acc, 8);
      if (lane == 0) g1loc[ridx] = acc + g1bpre[ridx] + b1loc[ridx];
    }
    __syncthreads();

    // ---- 5: PW1 (own 16 cols) -> tagged h1n store -------------------------
    if (tid < JW) {
      float gi = g1loc[tid];
      float gf = g1loc[16 + tid];
      float gg = g1loc[32 + tid];
      float go = g1loc[48 + tid];
      float cn = sigf(gf) * c1loc[tid] + sigf(gi) * tanhf(gg);
      c1loc[tid] = cn;
      tag_store(&HB1[p * 512 + j0 + tid], tg, sigf(go) * tanhf(cn));
    }

    // ---- 6: shadow-1 (hides h1n hop): G0pre(i+1); W2[i] -> w2s ------------
#pragma unroll 1
    for (int it = 0; it < 2; ++it) {
      int task = it * NT + tid;
      int ridx = task >> 3, lane = task & 7;
      int g = ridx >> 4, dj = ridx & 15;
      int row = g * H + j0 + dj;
      const float* wr = Whh0 + (size_t)row * H + lane * 64;
      const float* hv = h0full + lane * 64;
      float acc = 0.f;
#pragma unroll
      for (int k = 0; k < 64; k += 4) {
        float4 w4 = *(const float4*)(wr + k);
        acc += w4.x * hv[k] + w4.y * hv[k + 1] + w4.z * hv[k + 2] + w4.w * hv[k + 3];
      }
      acc += __shfl_xor(acc, 1);
      acc += __shfl_xor(acc, 2);
      acc += __shfl_xor(acc, 4);
      if (lane == 0) g0pre[ridx] = acc + b0loc[ridx];
    }
    {
      const float* wsrc = cW2 + (size_t)i * H * OPS;
#pragma unroll
      for (int r = 0; r < 6; ++r) {
        int q = tid + 256 * r;
        float4 v = *(const float4*)(wsrc + 4 * q);
        int f = 4 * q;
        w2s[(f / 12) * 13 + (f % 12)]             = v.x;
        w2s[((f + 1) / 12) * 13 + ((f + 1) % 12)] = v.y;
        w2s[((f + 2) / 12) * 13 + ((f + 2) % 12)] = v.z;
        w2s[((f + 3) / 12) * 13 + ((f + 3) % 12)] = v.w;
      }
    }

    // ---- 7: poll full h1n -------------------------------------------------
    {
      int t2 = tid * 2;
      tag_poll2(&HB1[p * 512 + t2], &HB1[p * 512 + t2 + 1], tg,
                shp1[t2], shp1[t2 + 1]);
    }
    __syncthreads();

    // ---- 8: phase C: 16 HM cols in 4 groups (round-9 order per col) -------
#pragma unroll 1
    for (int cg = 0; cg < 4; ++cg) {
      {
        int wv = tid >> 6, ln = tid & 63;
        int jl = ln & 3, ks = ln >> 2;
        int kbase = wv * 128 + ks * 8;
        float acc = 0.f;
#pragma unroll
        for (int t = 0; t < 8; ++t) {
          int k = kbase + t;
          acc += shp1[k] * w1s[k * 17 + cg * 4 + jl];
        }
        acc += __shfl_xor(acc, 4);
        acc += __shfl_xor(acc, 8);
        acc += __shfl_xor(acc, 16);
        acc += __shfl_xor(acc, 32);
        if (ln < 4) spart[wv][ln] = acc;
      }
      __syncthreads();
      if (tid < 4) {
        float s = spart[0][tid] + spart[1][tid] + spart[2][tid] + spart[3][tid];
        s += cb1[(size_t)i * H + j0 + cg * 4 + tid];
        tag_store(&HMB[p * 512 + j0 + cg * 4 + tid], tg, fmaxf(s, 0.f));
      }
      __syncthreads();
    }

    // ---- 9: shadow-2: W1[i+1] stream; G1Bpre(i+1) -------------------------
    if (i + 1 < E) {
      float4 v[8];
      if (use_w1t) {
        const float* wt = W1T + ((size_t)((i + 1) * 32 + bid) * 512 << 4);
#pragma unroll
        for (int r = 0; r < 8; ++r) {
          int q = r * NT + tid;
          v[r] = *(const float4*)(wt + (size_t)q * 4);
        }
      } else {
        const float* wb = cW1 + (size_t)(i + 1) * H * H;
#pragma unroll
        for (int r = 0; r < 8; ++r) {
          int q = r * NT + tid;
          int k = q >> 2, jc0 = (q & 3) * 4;
          v[r] = *(const float4*)(wb + (size_t)k * H + j0 + jc0);
        }
      }
#pragma unroll 1
      for (int it = 0; it < 2; ++it) {
        int task = it * NT + tid;
        int ridx = task >> 3, lane = task & 7;
        int g = ridx >> 4, dj = ridx & 15;
        int row = g * H + j0 + dj;
        const float* wr = Whh1 + (size_t)row * H + lane * 64;
        const float* hv = shp1 + lane * 64;
        float acc = 0.f;
#pragma unroll
        for (int k = 0; k < 64; k += 4) {
          float4 w4 = *(const float4*)(wr + k);
          acc += w4.x * hv[k] + w4.y * hv[k + 1] + w4.z * hv[k + 2] + w4.w * hv[k + 3];
        }
        acc += __shfl_xor(acc, 1);
        acc += __shfl_xor(acc, 2);
        acc += __shfl_xor(acc, 4);
        if (lane == 0) g1bpre[ridx] = acc;
      }
#pragma unroll
      for (int r = 0; r < 8; ++r) {
        int q = r * NT + tid;
        int k = q >> 2, jc0 = (q & 3) * 4;
        float* d = &w1s[k * 17 + jc0];
        d[0] = v[r].x; d[1] = v[r].y; d[2] = v[r].z; d[3] = v[r].w;
      }
    }
    __syncthreads();
  }

  // ---- final sampling (step E-1); w2s = W2[E-1] ---------------------------
  if (bid == 0) {
    const int q = (E - 1) & 1;
    int t2 = tid * 2;
    tag_poll2(&HMB[q * 512 + t2], &HMB[q * 512 + t2 + 1], (unsigned)E,
              hm[t2], hm[t2 + 1]);
    __syncthreads();
    if (tid < 64) {
      float lg[OPS];
#pragma unroll
      for (int o = 0; o < OPS; ++o) lg[o] = 0.f;
#pragma unroll
      for (int jj = 0; jj < 8; ++jj) {
        int j = jj * 64 + tid;
        float hmv = hm[j];
        const float* w2r = &w2s[j * 13];
#pragma unroll
        for (int o = 0; o < OPS; ++o) lg[o] += hmv * w2r[o];
      }
#pragma unroll
      for (int s = 1; s < 64; s <<= 1) {
#pragma unroll
        for (int o = 0; o < OPS; ++o) lg[o] += __shfl_xor(lg[o], s);
      }
#pragma unroll
      for (int o = 0; o < OPS; ++o) lg[o] = (lg[o] + cb2[(E - 1) * OPS + o]) * invt;
      float mx = lg[0];
#pragma unroll
      for (int o = 1; o < OPS; ++o) mx = fmaxf(mx, lg[o]);
      float se = 0.f;
#pragma unroll
      for (int o = 0; o < OPS; ++o) se += expf(lg[o] - mx);
      float logZ = mx + logf(se);
      float best = -1e30f; int act = 0;
#pragma unroll
      for (int o = 0; o < OPS; ++o) {
        float v = lg[o] + gum[(E - 1) * OPS + o];
        if (v > best) { best = v; act = o; }
      }
      if (tid == 0) {
        float lp = lg[act] - logZ;
        float ent = 0.f;
        for (int o = 0; o < OPS; ++o) {
          float l2 = lg[o] - logZ;
          ent -= expf(l2) * l2;
        }
        out[E - 1]     = (float)act;
        out[2 * E - 1] = lp;
        out[3 * E - 1] = ent;
      }
    }
  }
}

// ===========================================================================
extern "C" void kernel_launch(void* const* d_in, const int* in_sizes, int n_in,
                              void* d_out, int out_size, void* d_ws, size_t ws_size,
                              hipStream_t stream) {
  (void)out_size;
  float* out = (float*)d_out;
  float* ws  = (float*)d_ws;

  (void)hipGetLastError();

  static const long long expect[16] = {
      1, 1024, 1024, 1048576, 1048576, 2048, 2048,
      1048576, 1048576, 2048, 2048, 6144,
      29360128, 57344, 688128, 1344 };
  int bad = -1;
  if (n_in != 16) bad = 99;
  else {
    for (int i = 0; i < 16; ++i)
      if ((long long)in_sizes[i] != expect[i]) { bad = i; break; }
  }

  k_init<<<12, 256, 0, stream>>>((u64*)(ws + 16));
  if (bad >= 0) {
    k_diag<<<1, 64, 0, stream>>>(out, 80000.0f + (float)bad);
    return;
  }

  const size_t need = (size_t)WS_W1T_F * 4 + (size_t)29360128 * 4;
  int use_w1t = (ws_size >= need) ? 1 : 0;
  if (use_w1t) {
    // 29360128 floats / 4 per thread / 256 per block = 28672 blocks
    k_w1t<<<28672, 256, 0, stream>>>((const float*)d_in[12], ws + WS_W1T_F);
  }

  policy_persist<<<NWG, NT, 0, stream>>>(
      d_in[0],
      (const float*)d_in[1],  (const float*)d_in[2],
      (const float*)d_in[3],  (const float*)d_in[4],
      (const float*)d_in[5],  (const float*)d_in[6],
      (const float*)d_in[7],  (const float*)d_in[8],
      (const float*)d_in[9],  (const float*)d_in[10],
      (const float*)d_in[11], (const float*)d_in[12],
      (const float*)d_in[13], (const float*)d_in[14],
      (const float*)d_in[15],
      out, ws, use_w1t);

  hipError_t e = hipGetLastError();
  if (e != hipSuccess) {
    k_diag<<<1, 64, 0, stream>>>(out, 90000.0f + (float)(int)e);
  }
}

// Round 12
// 1142.068 us; speedup vs baseline: 2.7115x; 1.9559x over previous
//
#include <hip/hip_runtime.h>
#include <math.h>

#define H    512
#define OPS  12
#define E    112
#define NWG  128
#define NT   256

typedef unsigned long long u64;
typedef unsigned int u32x4 __attribute__((ext_vector_type(4)));

// ws layout: 16-float header | 3072 tagged u64 | W1T (optional, 112 MB)
#define TW_HB0   0                    // [2][512] h0n
#define TW_HB1   1024                 // [2][512] h1n
#define TW_HMB   2048                 // [2][512] controller hidden
#define TW_TOTAL 3072
#define WS_W1T_F (16 + 2 * TW_TOTAL)  // float offset of W1T region

__device__ __forceinline__ float sigf(float x) { return 1.f / (1.f + expf(-x)); }

// JAX threefry2x32, key = PRNGKey(42) = (0,42), 20 rounds
__device__ __forceinline__ void threefry_42(unsigned x0, unsigned x1,
                                            unsigned& o0, unsigned& o1) {
  const unsigned k0 = 0u, k1 = 42u;
  const unsigned k2 = k0 ^ k1 ^ 0x1BD11BDAu;
  x0 += k0; x1 += k1;
#define TF_R(rot) { x0 += x1; x1 = (x1 << rot) | (x1 >> (32 - rot)); x1 ^= x0; }
  TF_R(13) TF_R(15) TF_R(26) TF_R(6)
  x0 += k1; x1 += k2 + 1u;
  TF_R(17) TF_R(29) TF_R(16) TF_R(24)
  x0 += k2; x1 += k0 + 2u;
  TF_R(13) TF_R(15) TF_R(26) TF_R(6)
  x0 += k0; x1 += k1 + 3u;
  TF_R(17) TF_R(29) TF_R(16) TF_R(24)
  x0 += k1; x1 += k2 + 4u;
  TF_R(13) TF_R(15) TF_R(26) TF_R(6)
  x0 += k2; x1 += k0 + 5u;
#undef TF_R
  o0 = x0; o1 = x1;
}

__device__ __forceinline__ float bits_to_gumbel(unsigned bits) {
  unsigned fb = (bits >> 9) | 0x3f800000u;
  float u = __uint_as_float(fb) - 1.0f;
  u = u + 1.17549435e-38f;
  u = fmaxf(1.17549435e-38f, u);
  return -logf(-logf(u));
}

__device__ __forceinline__ float decode_temp(const void* temp_p) {
  float tf = *(const float*)temp_p;
  float a = fabsf(tf);
  if (a > 1e-6f && a < 1e6f) return tf;
  int ti = *(const int*)temp_p;
  if (ti != 0 && ti > -1000000 && ti < 1000000) return (float)ti;
  double td = *(const double*)temp_p;
  double ad = fabs(td);
  if (ad > 1e-6 && ad < 1e6) return (float)td;
  return 1.0f;
}

// MALL-coherent tagged-word transport (tag<<32 | float bits)
__device__ __forceinline__ void tag_store(u64* p, unsigned tag, float f) {
  u64 v = ((u64)tag << 32) | (u64)__float_as_uint(f);
  __hip_atomic_store(p, v, __ATOMIC_RELAXED, __HIP_MEMORY_SCOPE_SYSTEM);
}
// poll TWO adjacent tagged words with ONE 16B cache-bypassing load
__device__ __forceinline__ void tag_poll2(const u64* p, unsigned tag,
                                          float& f0, float& f1) {
  u32x4 v;
  for (;;) {
    asm volatile("global_load_dwordx4 %0, %1, off sc0 sc1\n\t"
                 "s_waitcnt vmcnt(0)"
                 : "=&v"(v) : "v"(p) : "memory");
    if (v.y == tag && v.w == tag) break;
    __builtin_amdgcn_s_sleep(1);
  }
  f0 = __uint_as_float(v.x);
  f1 = __uint_as_float(v.z);
}

__global__ void k_init(u64* tw) {
  int t = blockIdx.x * blockDim.x + threadIdx.x;
  if (t < TW_TOTAL) tw[t] = 0ull;
}
__global__ void k_diag(float* out, float v) {
  if (threadIdx.x == 0 && blockIdx.x == 0) out[0] = v;
}

// transpose cW1 -> W1T[((i*32+b)*512 + k)*16 + jc] = cW1[i][k][b*16+jc]
__global__ void __launch_bounds__(NT)
k_w1t(const float* __restrict__ cW1, float* __restrict__ w1t) {
  int t = blockIdx.x * NT + threadIdx.x;            // float4 index
  size_t e0 = (size_t)t * 4;
  int i = (int)(e0 >> 18);
  int rem = (int)(e0 & 262143);
  int k = rem >> 9, j = rem & 511;
  int b = j >> 4, jc = j & 15;
  float4 v = *(const float4*)(cW1 + e0);
  size_t dst = (((size_t)(i * 32 + b) * 512 + k) << 4) + jc;
  *(float4*)(w1t + dst) = v;
}

// ===========================================================================
__global__ void __launch_bounds__(NT)
policy_persist(const void* temp_p,
               const float* __restrict__ h0_in, const float* __restrict__ c0_in,
               const float* __restrict__ Wih0,  const float* __restrict__ Whh0,
               const float* __restrict__ bih0,  const float* __restrict__ bhh0,
               const float* __restrict__ Wih1,  const float* __restrict__ Whh1,
               const float* __restrict__ bih1,  const float* __restrict__ bhh1,
               const float* __restrict__ emb,   const float* __restrict__ cW1,
               const float* __restrict__ cb1,   const float* __restrict__ cW2,
               const float* __restrict__ cb2,
               float* __restrict__ out, float* ws, int use_w1t) {
  __shared__ __align__(16) float h0full[H], shp1[H], hm[H];
  __shared__ float g0pre[16], g1bpre[16], g1loc[16];
  __shared__ float ewloc[12 * 16], b0loc[16], b1loc[16];
  __shared__ float gum[E * OPS];
  __shared__ float w1s[512 * 5];          // W1[i] 4-col slice, stride-5
  __shared__ float w2s[512 * 13];         // W2[i], stride-13
  __shared__ float c0loc[4], c1loc[4];
  __shared__ float spart[4][4];
  __shared__ int s_act;

  const int tid = threadIdx.x;
  const int bid = blockIdx.x;
  const int j0  = bid * 4;                       // owned h-columns
  const int cb  = (bid & 7) * 16 + (bid >> 3);   // XCD-grouped HM col-block
  const float invt = 1.f / decode_temp(temp_p);

  u64* HB0 = (u64*)(ws + 16) + TW_HB0;
  u64* HB1 = (u64*)(ws + 16) + TW_HB1;
  u64* HMB = (u64*)(ws + 16) + TW_HMB;
  const float* W1T = ws + WS_W1T_F;
  const int bb = cb >> 2, boff = (cb & 3) * 4;   // W1T 16-block / 4-col offset

  // ---------------- setup (all WG-local) -----------------------------------
  for (int p = tid; p < E * OPS; p += NT) {
    unsigned y0, y1;
    threefry_42(0u, (unsigned)p, y0, y1);
    gum[p] = bits_to_gumbel(y0 ^ y1);
  }
  for (int j = tid; j < H; j += NT) {
    h0full[j] = h0_in[j];
    shp1[j]   = h0_in[H + j];
  }
  if (tid < 192) {
    int a = tid / 16, ridx = tid % 16;
    int g = ridx >> 2, dj = ridx & 3;
    int row = g * H + j0 + dj;
    const float* er = emb + a * H;
    const float* wr = Wih0 + (size_t)row * H;
    float acc = 0.f;
    for (int k = 0; k < H; k += 4) {
      float4 e4 = *(const float4*)(er + k);
      float4 w4 = *(const float4*)(wr + k);
      acc += e4.x * w4.x + e4.y * w4.y + e4.z * w4.z + e4.w * w4.w;
    }
    ewloc[tid] = acc;
  }
  if (tid < 16) {
    int g = tid >> 2, dj = tid & 3;
    int row = g * H + j0 + dj;
    b0loc[tid] = bih0[row] + bhh0[row];
    b1loc[tid] = bih1[row] + bhh1[row];
  }
  if (tid < 4) {
    c0loc[tid] = c0_in[j0 + tid];
    c1loc[tid] = c0_in[H + j0 + tid];
  }
  __syncthreads();

  // G-pre(0) combined pass + W1[0] prefetch (round-9 math)
  {
    int rowidx = tid >> 3, lane = tid & 7;
    int cell = rowidx >> 4, ridx = rowidx & 15;
    int g = ridx >> 2, dj = ridx & 3;
    int row = g * H + j0 + dj;
    const float* wr = (cell ? Whh1 : Whh0) + (size_t)row * H + lane * 64;
    const float* hv = (cell ? shp1 : h0full) + lane * 64;
    float acc = 0.f;
#pragma unroll
    for (int k = 0; k < 64; k += 4) {
      float4 w4 = *(const float4*)(wr + k);
      acc += w4.x * hv[k] + w4.y * hv[k + 1] + w4.z * hv[k + 2] + w4.w * hv[k + 3];
    }
    acc += __shfl_xor(acc, 1);
    acc += __shfl_xor(acc, 2);
    acc += __shfl_xor(acc, 4);
    if (lane == 0) {
      if (cell == 0) g0pre[ridx] = acc + b0loc[ridx];
      else           g1bpre[ridx] = acc;
    }
    float4 r0, r1;
    if (use_w1t) {
      const float* wt = W1T + (((size_t)bb * 512) << 4) + boff;
      r0 = *(const float4*)(wt + ((size_t)tid << 4));
      r1 = *(const float4*)(wt + ((size_t)(tid + 256) << 4));
    } else {
      const float* wb = cW1 + (size_t)cb * 4;
      r0 = *(const float4*)(wb + (size_t)tid * H);
      r1 = *(const float4*)(wb + (size_t)(tid + 256) * H);
    }
    int k0 = tid * 5, k1 = (tid + 256) * 5;
    w1s[k0] = r0.x; w1s[k0 + 1] = r0.y; w1s[k0 + 2] = r0.z; w1s[k0 + 3] = r0.w;
    w1s[k1] = r1.x; w1s[k1 + 1] = r1.y; w1s[k1 + 2] = r1.z; w1s[k1 + 3] = r1.w;
  }
  __syncthreads();

#pragma unroll 1
  for (int i = 0; i < E; ++i) {
    const int p = i & 1;
    const unsigned tg = (unsigned)(i + 1);

    // ---- 1: sample step i-1 (poll HM tag i; w2s = W2[i-1]) ----------------
    if (i > 0) {
      const int q = (i - 1) & 1;
      int t2 = tid * 2;
      tag_poll2(&HMB[q * 512 + t2], (unsigned)i, hm[t2], hm[t2 + 1]);
      __syncthreads();
      if (tid < 64) {
        float lg[OPS];
#pragma unroll
        for (int o = 0; o < OPS; ++o) lg[o] = 0.f;
#pragma unroll
        for (int jj = 0; jj < 8; ++jj) {
          int j = jj * 64 + tid;
          float hmv = hm[j];
          const float* w2r = &w2s[j * 13];
#pragma unroll
          for (int o = 0; o < OPS; ++o) lg[o] += hmv * w2r[o];
        }
#pragma unroll
        for (int s = 1; s < 64; s <<= 1) {
#pragma unroll
          for (int o = 0; o < OPS; ++o) lg[o] += __shfl_xor(lg[o], s);
        }
#pragma unroll
        for (int o = 0; o < OPS; ++o) lg[o] = (lg[o] + cb2[(i - 1) * OPS + o]) * invt;
        float mx = lg[0];
#pragma unroll
        for (int o = 1; o < OPS; ++o) mx = fmaxf(mx, lg[o]);
        float se = 0.f;
#pragma unroll
        for (int o = 0; o < OPS; ++o) se += expf(lg[o] - mx);
        float logZ = mx + logf(se);
        float best = -1e30f; int act = 0;
#pragma unroll
        for (int o = 0; o < OPS; ++o) {
          float v = lg[o] + gum[(i - 1) * OPS + o];
          if (v > best) { best = v; act = o; }
        }
        if (tid == 0) {
          s_act = act;
          if (bid == 0) {
            float lp = lg[act] - logZ;
            float ent = 0.f;
            for (int o = 0; o < OPS; ++o) {
              float l2 = lg[o] - logZ;
              ent -= expf(l2) * l2;
            }
            out[i - 1]         = (float)act;
            out[E + i - 1]     = lp;
            out[2 * E + i - 1] = ent;
          }
        }
      }
      // no barrier: s_act produced and consumed within wave 0
    }

    // ---- 2: PW0 (own 4 cols) -> tagged h0n store --------------------------
    if (tid < 4) {
      int a = (i > 0) ? s_act : -1;
      float gi = g0pre[tid];
      float gf = g0pre[4 + tid];
      float gg = g0pre[8 + tid];
      float go = g0pre[12 + tid];
      if (a >= 0) {
        gi += ewloc[a * 16 + tid];
        gf += ewloc[a * 16 + 4 + tid];
        gg += ewloc[a * 16 + 8 + tid];
        go += ewloc[a * 16 + 12 + tid];
      }
      float cn = sigf(gf) * c0loc[tid] + sigf(gi) * tanhf(gg);
      c0loc[tid] = cn;
      tag_store(&HB0[p * 512 + j0 + tid], tg, sigf(go) * tanhf(cn));
    }

    // ---- 3: poll full h0n -------------------------------------------------
    {
      int t2 = tid * 2;
      tag_poll2(&HB0[p * 512 + t2], tg, h0full[t2], h0full[t2 + 1]);
    }
    __syncthreads();

    // ---- 4: G1 = Wih1@h0n + G1Bpre + B1 (own 16 rows, 16 lanes/row) -------
    {
      int ridx = tid >> 4, lane = tid & 15;
      int g = ridx >> 2, dj = ridx & 3;
      int row = g * H + j0 + dj;
      const float* wr = Wih1 + (size_t)row * H + lane * 32;
      const float* hv = h0full + lane * 32;
      float acc = 0.f;
#pragma unroll
      for (int k = 0; k < 32; k += 4) {
        float4 w4 = *(const float4*)(wr + k);
        acc += w4.x * hv[k] + w4.y * hv[k + 1] + w4.z * hv[k + 2] + w4.w * hv[k + 3];
      }
      acc += __shfl_xor(acc, 1);
      acc += __shfl_xor(acc, 2);
      acc += __shfl_xor(acc, 4);
      acc += __shfl_xor(acc, 8);
      if (lane == 0) g1loc[ridx] = acc + g1bpre[ridx] + b1loc[ridx];
    }
    __syncthreads();

    // ---- 5: PW1 (own 4 cols) -> tagged h1n store --------------------------
    if (tid < 4) {
      float gi = g1loc[tid];
      float gf = g1loc[4 + tid];
      float gg = g1loc[8 + tid];
      float go = g1loc[12 + tid];
      float cn = sigf(gf) * c1loc[tid] + sigf(gi) * tanhf(gg);
      c1loc[tid] = cn;
      tag_store(&HB1[p * 512 + j0 + tid], tg, sigf(go) * tanhf(cn));
    }

    // ---- 6: shadow-1: issue W1[i+1] loads; G0pre(i+1); W2[i] -> w2s -------
    float4 v0, v1;
    if (i + 1 < E) {
      if (use_w1t) {
        const float* wt = W1T + (((size_t)((i + 1) * 32 + bb) * 512) << 4) + boff;
        v0 = *(const float4*)(wt + ((size_t)tid << 4));
        v1 = *(const float4*)(wt + ((size_t)(tid + 256) << 4));
      } else {
        const float* wb = cW1 + (size_t)(i + 1) * H * H + (size_t)cb * 4;
        v0 = *(const float4*)(wb + (size_t)tid * H);
        v1 = *(const float4*)(wb + (size_t)(tid + 256) * H);
      }
    }
    if (tid < 128) {
      int ridx = tid >> 3, lane = tid & 7;
      int g = ridx >> 2, dj = ridx & 3;
      int row = g * H + j0 + dj;
      const float* wr = Whh0 + (size_t)row * H + lane * 64;
      const float* hv = h0full + lane * 64;
      float acc = 0.f;
#pragma unroll
      for (int k = 0; k < 64; k += 4) {
        float4 w4 = *(const float4*)(wr + k);
        acc += w4.x * hv[k] + w4.y * hv[k + 1] + w4.z * hv[k + 2] + w4.w * hv[k + 3];
      }
      acc += __shfl_xor(acc, 1);
      acc += __shfl_xor(acc, 2);
      acc += __shfl_xor(acc, 4);
      if (lane == 0) g0pre[ridx] = acc + b0loc[ridx];
    }
    {
      const float* wsrc = cW2 + (size_t)i * H * OPS;
#pragma unroll
      for (int r = 0; r < 6; ++r) {
        int q = tid + 256 * r;
        float4 v = *(const float4*)(wsrc + 4 * q);
        int f = 4 * q;
        w2s[(f / 12) * 13 + (f % 12)]             = v.x;
        w2s[((f + 1) / 12) * 13 + ((f + 1) % 12)] = v.y;
        w2s[((f + 2) / 12) * 13 + ((f + 2) % 12)] = v.z;
        w2s[((f + 3) / 12) * 13 + ((f + 3) % 12)] = v.w;
      }
    }

    // ---- 7: poll full h1n -------------------------------------------------
    {
      int t2 = tid * 2;
      tag_poll2(&HB1[p * 512 + t2], tg, shp1[t2], shp1[t2 + 1]);
    }
    __syncthreads();

    // ---- 8: phase C: HM own 4 cols from LDS W1 ----------------------------
    {
      int wv = tid >> 6, ln = tid & 63;
      int jl = ln & 3, ks = ln >> 2;
      int kbase = wv * 128 + ks * 8;
      float acc = 0.f;
#pragma unroll
      for (int t = 0; t < 8; ++t) {
        int k = kbase + t;
        acc += shp1[k] * w1s[k * 5 + jl];
      }
      acc += __shfl_xor(acc, 4);
      acc += __shfl_xor(acc, 8);
      acc += __shfl_xor(acc, 16);
      acc += __shfl_xor(acc, 32);
      if (ln < 4) spart[wv][ln] = acc;
    }
    __syncthreads();
    if (tid < 4) {
      float s = spart[0][tid] + spart[1][tid] + spart[2][tid] + spart[3][tid];
      s += cb1[(size_t)i * H + cb * 4 + tid];
      tag_store(&HMB[p * 512 + cb * 4 + tid], tg, fmaxf(s, 0.f));
    }

    // ---- 9: shadow-2: G1Bpre(i+1); commit W1[i+1] -> w1s ------------------
    if (i + 1 < E) {
      if (tid < 128) {
        int ridx = tid >> 3, lane = tid & 7;
        int g = ridx >> 2, dj = ridx & 3;
        int row = g * H + j0 + dj;
        const float* wr = Whh1 + (size_t)row * H + lane * 64;
        const float* hv = shp1 + lane * 64;
        float acc = 0.f;
#pragma unroll
        for (int k = 0; k < 64; k += 4) {
          float4 w4 = *(const float4*)(wr + k);
          acc += w4.x * hv[k] + w4.y * hv[k + 1] + w4.z * hv[k + 2] + w4.w * hv[k + 3];
        }
        acc += __shfl_xor(acc, 1);
        acc += __shfl_xor(acc, 2);
        acc += __shfl_xor(acc, 4);
        if (lane == 0) g1bpre[ridx] = acc;
      }
      int k0 = tid * 5, k1 = (tid + 256) * 5;
      w1s[k0] = v0.x; w1s[k0 + 1] = v0.y; w1s[k0 + 2] = v0.z; w1s[k0 + 3] = v0.w;
      w1s[k1] = v1.x; w1s[k1 + 1] = v1.y; w1s[k1 + 2] = v1.z; w1s[k1 + 3] = v1.w;
    }
    __syncthreads();
  }

  // ---- final sampling (step E-1); w2s = W2[E-1] ---------------------------
  if (bid == 0) {
    const int q = (E - 1) & 1;
    int t2 = tid * 2;
    tag_poll2(&HMB[q * 512 + t2], (unsigned)E, hm[t2], hm[t2 + 1]);
    __syncthreads();
    if (tid < 64) {
      float lg[OPS];
#pragma unroll
      for (int o = 0; o < OPS; ++o) lg[o] = 0.f;
#pragma unroll
      for (int jj = 0; jj < 8; ++jj) {
        int j = jj * 64 + tid;
        float hmv = hm[j];
        const float* w2r = &w2s[j * 13];
#pragma unroll
        for (int o = 0; o < OPS; ++o) lg[o] += hmv * w2r[o];
      }
#pragma unroll
      for (int s = 1; s < 64; s <<= 1) {
#pragma unroll
        for (int o = 0; o < OPS; ++o) lg[o] += __shfl_xor(lg[o], s);
      }
#pragma unroll
      for (int o = 0; o < OPS; ++o) lg[o] = (lg[o] + cb2[(E - 1) * OPS + o]) * invt;
      float mx = lg[0];
#pragma unroll
      for (int o = 1; o < OPS; ++o) mx = fmaxf(mx, lg[o]);
      float se = 0.f;
#pragma unroll
      for (int o = 0; o < OPS; ++o) se += expf(lg[o] - mx);
      float logZ = mx + logf(se);
      float best = -1e30f; int act = 0;
#pragma unroll
      for (int o = 0; o < OPS; ++o) {
        float v = lg[o] + gum[(E - 1) * OPS + o];
        if (v > best) { best = v; act = o; }
      }
      if (tid == 0) {
        float lp = lg[act] - logZ;
        float ent = 0.f;
        for (int o = 0; o < OPS; ++o) {
          float l2 = lg[o] - logZ;
          ent -= expf(l2) * l2;
        }
        out[E - 1]     = (float)act;
        out[2 * E - 1] = lp;
        out[3 * E - 1] = ent;
      }
    }
  }
}

// ===========================================================================
extern "C" void kernel_launch(void* const* d_in, const int* in_sizes, int n_in,
                              void* d_out, int out_size, void* d_ws, size_t ws_size,
                              hipStream_t stream) {
  (void)out_size;
  float* out = (float*)d_out;
  float* ws  = (float*)d_ws;

  (void)hipGetLastError();

  static const long long expect[16] = {
      1, 1024, 1024, 1048576, 1048576, 2048, 2048,
      1048576, 1048576, 2048, 2048, 6144,
      29360128, 57344, 688128, 1344 };
  int bad = -1;
  if (n_in != 16) bad = 99;
  else {
    for (int i = 0; i < 16; ++i)
      if ((long long)in_sizes[i] != expect[i]) { bad = i; break; }
  }

  k_init<<<12, 256, 0, stream>>>((u64*)(ws + 16));
  if (bad >= 0) {
    k_diag<<<1, 64, 0, stream>>>(out, 80000.0f + (float)bad);
    return;
  }

  const size_t need = (size_t)WS_W1T_F * 4 + (size_t)29360128 * 4;
  int use_w1t = (ws_size >= need) ? 1 : 0;
  if (use_w1t) {
    k_w1t<<<28672, 256, 0, stream>>>((const float*)d_in[12], ws + WS_W1T_F);
  }

  policy_persist<<<NWG, NT, 0, stream>>>(
      d_in[0],
      (const float*)d_in[1],  (const float*)d_in[2],
      (const float*)d_in[3],  (const float*)d_in[4],
      (const float*)d_in[5],  (const float*)d_in[6],
      (const float*)d_in[7],  (const float*)d_in[8],
      (const float*)d_in[9],  (const float*)d_in[10],
      (const float*)d_in[11], (const float*)d_in[12],
      (const float*)d_in[13], (const float*)d_in[14],
      (const float*)d_in[15],
      out, ws, use_w1t);

  hipError_t e = hipGetLastError();
  if (e != hipSuccess) {
    k_diag<<<1, 64, 0, stream>>>(out, 90000.0f + (float)(int)e);
  }
}

// Round 13
// 1091.534 us; speedup vs baseline: 2.8370x; 1.0463x over previous
//
#include <hip/hip_runtime.h>
#include <math.h>

#define H    512
#define OPS  12
#define E    112
#define NWG  128
#define NT   256

typedef unsigned long long u64;
typedef unsigned int u32x4 __attribute__((ext_vector_type(4)));

// ws layout: 16-float header | 3072 tagged u64
#define TW_HB0   0                    // [2][512] h0n
#define TW_HB1   1024                 // [2][512] h1n
#define TW_HMB   2048                 // [2][512] controller hidden
#define TW_TOTAL 3072

__device__ __forceinline__ float sigf(float x) { return 1.f / (1.f + expf(-x)); }

// JAX threefry2x32, key = PRNGKey(42) = (0,42), 20 rounds
__device__ __forceinline__ void threefry_42(unsigned x0, unsigned x1,
                                            unsigned& o0, unsigned& o1) {
  const unsigned k0 = 0u, k1 = 42u;
  const unsigned k2 = k0 ^ k1 ^ 0x1BD11BDAu;
  x0 += k0; x1 += k1;
#define TF_R(rot) { x0 += x1; x1 = (x1 << rot) | (x1 >> (32 - rot)); x1 ^= x0; }
  TF_R(13) TF_R(15) TF_R(26) TF_R(6)
  x0 += k1; x1 += k2 + 1u;
  TF_R(17) TF_R(29) TF_R(16) TF_R(24)
  x0 += k2; x1 += k0 + 2u;
  TF_R(13) TF_R(15) TF_R(26) TF_R(6)
  x0 += k0; x1 += k1 + 3u;
  TF_R(17) TF_R(29) TF_R(16) TF_R(24)
  x0 += k1; x1 += k2 + 4u;
  TF_R(13) TF_R(15) TF_R(26) TF_R(6)
  x0 += k2; x1 += k0 + 5u;
#undef TF_R
  o0 = x0; o1 = x1;
}

__device__ __forceinline__ float bits_to_gumbel(unsigned bits) {
  unsigned fb = (bits >> 9) | 0x3f800000u;
  float u = __uint_as_float(fb) - 1.0f;
  u = u + 1.17549435e-38f;
  u = fmaxf(1.17549435e-38f, u);
  return -logf(-logf(u));
}

__device__ __forceinline__ float decode_temp(const void* temp_p) {
  float tf = *(const float*)temp_p;
  float a = fabsf(tf);
  if (a > 1e-6f && a < 1e6f) return tf;
  int ti = *(const int*)temp_p;
  if (ti != 0 && ti > -1000000 && ti < 1000000) return (float)ti;
  double td = *(const double*)temp_p;
  double ad = fabs(td);
  if (ad > 1e-6 && ad < 1e6) return (float)td;
  return 1.0f;
}

// MALL-coherent tagged-word transport (tag<<32 | float bits)
__device__ __forceinline__ void tag_store(u64* p, unsigned tag, float f) {
  u64 v = ((u64)tag << 32) | (u64)__float_as_uint(f);
  __hip_atomic_store(p, v, __ATOMIC_RELAXED, __HIP_MEMORY_SCOPE_SYSTEM);
}
// poll TWO adjacent tagged words with ONE 16B cache-bypassing load
__device__ __forceinline__ void tag_poll2(const u64* p, unsigned tag,
                                          float& f0, float& f1) {
  u32x4 v;
  for (;;) {
    asm volatile("global_load_dwordx4 %0, %1, off sc0 sc1\n\t"
                 "s_waitcnt vmcnt(0)"
                 : "=&v"(v) : "v"(p) : "memory");
    if (v.y == tag && v.w == tag) break;
    __builtin_amdgcn_s_sleep(1);
  }
  f0 = __uint_as_float(v.x);
  f1 = __uint_as_float(v.z);
}

__global__ void k_init(u64* tw) {
  int t = blockIdx.x * blockDim.x + threadIdx.x;
  if (t < TW_TOTAL) tw[t] = 0ull;
}
__global__ void k_diag(float* out, float v) {
  if (threadIdx.x == 0 && blockIdx.x == 0) out[0] = v;
}

// ===========================================================================
__global__ void __launch_bounds__(NT)
policy_persist(const void* temp_p,
               const float* __restrict__ h0_in, const float* __restrict__ c0_in,
               const float* __restrict__ Wih0,  const float* __restrict__ Whh0,
               const float* __restrict__ bih0,  const float* __restrict__ bhh0,
               const float* __restrict__ Wih1,  const float* __restrict__ Whh1,
               const float* __restrict__ bih1,  const float* __restrict__ bhh1,
               const float* __restrict__ emb,   const float* __restrict__ cW1,
               const float* __restrict__ cb1,   const float* __restrict__ cW2,
               const float* __restrict__ cb2,
               float* __restrict__ out, float* ws) {
  __shared__ __align__(16) float h0full[H], shp1[H], hm[H];
  __shared__ float g0pre[16], g1bpre[16], g1loc[16];
  __shared__ float ewloc[12 * 16], b0loc[16], b1loc[16];
  __shared__ float gum[E * OPS];
  __shared__ float w1s[512 * 5];          // W1[i] 4-col slice, stride-5
  __shared__ float w2s[512 * 13];         // W2[i], stride-13
  __shared__ float c0loc[4], c1loc[4];
  __shared__ float spart[4][4];

  const int tid = threadIdx.x;
  const int bid = blockIdx.x;
  const int j0  = bid * 4;                       // owned h-columns
  const int cb  = (bid & 7) * 16 + (bid >> 3);   // XCD-grouped HM col-block
  const float invt = 1.f / decode_temp(temp_p);

  u64* HB0 = (u64*)(ws + 16) + TW_HB0;
  u64* HB1 = (u64*)(ws + 16) + TW_HB1;
  u64* HMB = (u64*)(ws + 16) + TW_HMB;

  // ---------------- setup (all WG-local) -----------------------------------
  for (int p = tid; p < E * OPS; p += NT) {
    unsigned y0, y1;
    threefry_42(0u, (unsigned)p, y0, y1);
    gum[p] = bits_to_gumbel(y0 ^ y1);
  }
  for (int j = tid; j < H; j += NT) {
    h0full[j] = h0_in[j];
    shp1[j]   = h0_in[H + j];
  }
  if (tid < 192) {
    int a = tid / 16, ridx = tid % 16;
    int g = ridx >> 2, dj = ridx & 3;
    int row = g * H + j0 + dj;
    const float* er = emb + a * H;
    const float* wr = Wih0 + (size_t)row * H;
    float acc = 0.f;
    for (int k = 0; k < H; k += 4) {
      float4 e4 = *(const float4*)(er + k);
      float4 w4 = *(const float4*)(wr + k);
      acc += e4.x * w4.x + e4.y * w4.y + e4.z * w4.z + e4.w * w4.w;
    }
    ewloc[tid] = acc;
  }
  if (tid < 16) {
    int g = tid >> 2, dj = tid & 3;
    int row = g * H + j0 + dj;
    b0loc[tid] = bih0[row] + bhh0[row];
    b1loc[tid] = bih1[row] + bhh1[row];
  }
  if (tid < 4) {
    c0loc[tid] = c0_in[j0 + tid];
    c1loc[tid] = c0_in[H + j0 + tid];
  }
  __syncthreads();

  // G-pre(0) combined pass + W1[0] prefetch (round-9 math)
  {
    int rowidx = tid >> 3, lane = tid & 7;
    int cell = rowidx >> 4, ridx = rowidx & 15;
    int g = ridx >> 2, dj = ridx & 3;
    int row = g * H + j0 + dj;
    const float* wr = (cell ? Whh1 : Whh0) + (size_t)row * H + lane * 64;
    const float* hv = (cell ? shp1 : h0full) + lane * 64;
    float acc = 0.f;
#pragma unroll
    for (int k = 0; k < 64; k += 4) {
      float4 w4 = *(const float4*)(wr + k);
      acc += w4.x * hv[k] + w4.y * hv[k + 1] + w4.z * hv[k + 2] + w4.w * hv[k + 3];
    }
    acc += __shfl_xor(acc, 1);
    acc += __shfl_xor(acc, 2);
    acc += __shfl_xor(acc, 4);
    if (lane == 0) {
      if (cell == 0) g0pre[ridx] = acc + b0loc[ridx];
      else           g1bpre[ridx] = acc;
    }
    const float* wb = cW1 + (size_t)cb * 4;
    float4 r0 = *(const float4*)(wb + (size_t)tid * H);
    float4 r1 = *(const float4*)(wb + (size_t)(tid + 256) * H);
    int k0 = tid * 5, k1 = (tid + 256) * 5;
    w1s[k0] = r0.x; w1s[k0 + 1] = r0.y; w1s[k0 + 2] = r0.z; w1s[k0 + 3] = r0.w;
    w1s[k1] = r1.x; w1s[k1 + 1] = r1.y; w1s[k1 + 2] = r1.z; w1s[k1 + 3] = r1.w;
  }
  __syncthreads();

#pragma unroll 1
  for (int i = 0; i < E; ++i) {
    const int p = i & 1;
    const unsigned tg = (unsigned)(i + 1);

    // ---- 1: sample step i-1; PW0 + h0n store issued BEFORE logZ/lp/ent ----
    if (i > 0) {
      const int q = (i - 1) & 1;
      int t2 = tid * 2;
      tag_poll2(&HMB[q * 512 + t2], (unsigned)i, hm[t2], hm[t2 + 1]);
      __syncthreads();
      if (tid < 64) {
        float lg[OPS];
#pragma unroll
        for (int o = 0; o < OPS; ++o) lg[o] = 0.f;
#pragma unroll
        for (int jj = 0; jj < 8; ++jj) {
          int j = jj * 64 + tid;
          float hmv = hm[j];
          const float* w2r = &w2s[j * 13];
#pragma unroll
          for (int o = 0; o < OPS; ++o) lg[o] += hmv * w2r[o];
        }
#pragma unroll
        for (int s = 1; s < 64; s <<= 1) {
#pragma unroll
          for (int o = 0; o < OPS; ++o) lg[o] += __shfl_xor(lg[o], s);
        }
#pragma unroll
        for (int o = 0; o < OPS; ++o) lg[o] = (lg[o] + cb2[(i - 1) * OPS + o]) * invt;
        // argmax FIRST (lg identical across lanes after reduce; gum is LDS)
        float best = -1e30f; int act = 0;
#pragma unroll
        for (int o = 0; o < OPS; ++o) {
          float v = lg[o] + gum[(i - 1) * OPS + o];
          if (v > best) { best = v; act = o; }
        }
        // PW0 (lanes 0-3) + h0n tagged store — critical path head
        if (tid < 4) {
          float gi = g0pre[tid]      + ewloc[act * 16 + tid];
          float gf = g0pre[4 + tid]  + ewloc[act * 16 + 4 + tid];
          float gg = g0pre[8 + tid]  + ewloc[act * 16 + 8 + tid];
          float go = g0pre[12 + tid] + ewloc[act * 16 + 12 + tid];
          float cn = sigf(gf) * c0loc[tid] + sigf(gi) * tanhf(gg);
          c0loc[tid] = cn;
          tag_store(&HB0[p * 512 + j0 + tid], tg, sigf(go) * tanhf(cn));
        }
        // lp/ent/out — off the chain, bid 0 only
        if (bid == 0) {
          float mx = lg[0];
#pragma unroll
          for (int o = 1; o < OPS; ++o) mx = fmaxf(mx, lg[o]);
          float se = 0.f;
#pragma unroll
          for (int o = 0; o < OPS; ++o) se += expf(lg[o] - mx);
          float logZ = mx + logf(se);
          if (tid == 0) {
            float lp = lg[act] - logZ;
            float ent = 0.f;
            for (int o = 0; o < OPS; ++o) {
              float l2 = lg[o] - logZ;
              ent -= expf(l2) * l2;
            }
            out[i - 1]         = (float)act;
            out[E + i - 1]     = lp;
            out[2 * E + i - 1] = ent;
          }
        }
      }
      // no barrier: everything above is wave-0-internal
    } else {
      // i == 0: PW0 without embedding contribution
      if (tid < 4) {
        float gi = g0pre[tid];
        float gf = g0pre[4 + tid];
        float gg = g0pre[8 + tid];
        float go = g0pre[12 + tid];
        float cn = sigf(gf) * c0loc[tid] + sigf(gi) * tanhf(gg);
        c0loc[tid] = cn;
        tag_store(&HB0[p * 512 + j0 + tid], tg, sigf(go) * tanhf(cn));
      }
    }

    // ---- 3: poll full h0n -------------------------------------------------
    {
      int t2 = tid * 2;
      tag_poll2(&HB0[p * 512 + t2], tg, h0full[t2], h0full[t2 + 1]);
    }
    __syncthreads();

    // ---- 4: G1 = Wih1@h0n + G1Bpre + B1 (own 16 rows, 16 lanes/row) -------
    {
      int ridx = tid >> 4, lane = tid & 15;
      int g = ridx >> 2, dj = ridx & 3;
      int row = g * H + j0 + dj;
      const float* wr = Wih1 + (size_t)row * H + lane * 32;
      const float* hv = h0full + lane * 32;
      float acc = 0.f;
#pragma unroll
      for (int k = 0; k < 32; k += 4) {
        float4 w4 = *(const float4*)(wr + k);
        acc += w4.x * hv[k] + w4.y * hv[k + 1] + w4.z * hv[k + 2] + w4.w * hv[k + 3];
      }
      acc += __shfl_xor(acc, 1);
      acc += __shfl_xor(acc, 2);
      acc += __shfl_xor(acc, 4);
      acc += __shfl_xor(acc, 8);
      if (lane == 0) g1loc[ridx] = acc + g1bpre[ridx] + b1loc[ridx];
    }
    __syncthreads();

    // ---- 5: PW1 (own 4 cols) -> tagged h1n store --------------------------
    if (tid < 4) {
      float gi = g1loc[tid];
      float gf = g1loc[4 + tid];
      float gg = g1loc[8 + tid];
      float go = g1loc[12 + tid];
      float cn = sigf(gf) * c1loc[tid] + sigf(gi) * tanhf(gg);
      c1loc[tid] = cn;
      tag_store(&HB1[p * 512 + j0 + tid], tg, sigf(go) * tanhf(cn));
    }

    // ---- 6: shadow-1: issue W1[i+1] loads; G0pre(i+1); W2[i] -> w2s -------
    float4 v0, v1;
    if (i + 1 < E) {
      const float* wb = cW1 + (size_t)(i + 1) * H * H + (size_t)cb * 4;
      v0 = *(const float4*)(wb + (size_t)tid * H);
      v1 = *(const float4*)(wb + (size_t)(tid + 256) * H);
    }
    if (tid < 128) {
      int ridx = tid >> 3, lane = tid & 7;
      int g = ridx >> 2, dj = ridx & 3;
      int row = g * H + j0 + dj;
      const float* wr = Whh0 + (size_t)row * H + lane * 64;
      const float* hv = h0full + lane * 64;
      float acc = 0.f;
#pragma unroll
      for (int k = 0; k < 64; k += 4) {
        float4 w4 = *(const float4*)(wr + k);
        acc += w4.x * hv[k] + w4.y * hv[k + 1] + w4.z * hv[k + 2] + w4.w * hv[k + 3];
      }
      acc += __shfl_xor(acc, 1);
      acc += __shfl_xor(acc, 2);
      acc += __shfl_xor(acc, 4);
      if (lane == 0) g0pre[ridx] = acc + b0loc[ridx];
    }
    {
      const float* wsrc = cW2 + (size_t)i * H * OPS;
#pragma unroll
      for (int r = 0; r < 6; ++r) {
        int q = tid + 256 * r;
        float4 v = *(const float4*)(wsrc + 4 * q);
        int f = 4 * q;
        w2s[(f / 12) * 13 + (f % 12)]             = v.x;
        w2s[((f + 1) / 12) * 13 + ((f + 1) % 12)] = v.y;
        w2s[((f + 2) / 12) * 13 + ((f + 2) % 12)] = v.z;
        w2s[((f + 3) / 12) * 13 + ((f + 3) % 12)] = v.w;
      }
    }

    // ---- 7: poll full h1n -------------------------------------------------
    {
      int t2 = tid * 2;
      tag_poll2(&HB1[p * 512 + t2], tg, shp1[t2], shp1[t2 + 1]);
    }
    __syncthreads();

    // ---- 8: phase C: HM own 4 cols from LDS W1 ----------------------------
    {
      int wv = tid >> 6, ln = tid & 63;
      int jl = ln & 3, ks = ln >> 2;
      int kbase = wv * 128 + ks * 8;
      float acc = 0.f;
#pragma unroll
      for (int t = 0; t < 8; ++t) {
        int k = kbase + t;
        acc += shp1[k] * w1s[k * 5 + jl];
      }
      acc += __shfl_xor(acc, 4);
      acc += __shfl_xor(acc, 8);
      acc += __shfl_xor(acc, 16);
      acc += __shfl_xor(acc, 32);
      if (ln < 4) spart[wv][ln] = acc;
    }
    __syncthreads();
    if (tid < 4) {
      float s = spart[0][tid] + spart[1][tid] + spart[2][tid] + spart[3][tid];
      s += cb1[(size_t)i * H + cb * 4 + tid];
      tag_store(&HMB[p * 512 + cb * 4 + tid], tg, fmaxf(s, 0.f));
    }

    // ---- 9: shadow-2: G1Bpre(i+1); commit W1[i+1] -> w1s ------------------
    if (i + 1 < E) {
      if (tid < 128) {
        int ridx = tid >> 3, lane = tid & 7;
        int g = ridx >> 2, dj = ridx & 3;
        int row = g * H + j0 + dj;
        const float* wr = Whh1 + (size_t)row * H + lane * 64;
        const float* hv = shp1 + lane * 64;
        float acc = 0.f;
#pragma unroll
        for (int k = 0; k < 64; k += 4) {
          float4 w4 = *(const float4*)(wr + k);
          acc += w4.x * hv[k] + w4.y * hv[k + 1] + w4.z * hv[k + 2] + w4.w * hv[k + 3];
        }
        acc += __shfl_xor(acc, 1);
        acc += __shfl_xor(acc, 2);
        acc += __shfl_xor(acc, 4);
        if (lane == 0) g1bpre[ridx] = acc;
      }
      int k0 = tid * 5, k1 = (tid + 256) * 5;
      w1s[k0] = v0.x; w1s[k0 + 1] = v0.y; w1s[k0 + 2] = v0.z; w1s[k0 + 3] = v0.w;
      w1s[k1] = v1.x; w1s[k1 + 1] = v1.y; w1s[k1 + 2] = v1.z; w1s[k1 + 3] = v1.w;
    }
    // no loop-end barrier: next step's HM/h0n poll barriers cover all
    // cross-wave LDS dependences (w1s/w2s/g0pre/g1bpre vs their readers).
  }

  // ---- final sampling (step E-1); w2s = W2[E-1] ---------------------------
  if (bid == 0) {
    const int q = (E - 1) & 1;
    int t2 = tid * 2;
    tag_poll2(&HMB[q * 512 + t2], (unsigned)E, hm[t2], hm[t2 + 1]);
    __syncthreads();
    if (tid < 64) {
      float lg[OPS];
#pragma unroll
      for (int o = 0; o < OPS; ++o) lg[o] = 0.f;
#pragma unroll
      for (int jj = 0; jj < 8; ++jj) {
        int j = jj * 64 + tid;
        float hmv = hm[j];
        const float* w2r = &w2s[j * 13];
#pragma unroll
        for (int o = 0; o < OPS; ++o) lg[o] += hmv * w2r[o];
      }
#pragma unroll
      for (int s = 1; s < 64; s <<= 1) {
#pragma unroll
        for (int o = 0; o < OPS; ++o) lg[o] += __shfl_xor(lg[o], s);
      }
#pragma unroll
      for (int o = 0; o < OPS; ++o) lg[o] = (lg[o] + cb2[(E - 1) * OPS + o]) * invt;
      float mx = lg[0];
#pragma unroll
      for (int o = 1; o < OPS; ++o) mx = fmaxf(mx, lg[o]);
      float se = 0.f;
#pragma unroll
      for (int o = 0; o < OPS; ++o) se += expf(lg[o] - mx);
      float logZ = mx + logf(se);
      float best = -1e30f; int act = 0;
#pragma unroll
      for (int o = 0; o < OPS; ++o) {
        float v = lg[o] + gum[(E - 1) * OPS + o];
        if (v > best) { best = v; act = o; }
      }
      if (tid == 0) {
        float lp = lg[act] - logZ;
        float ent = 0.f;
        for (int o = 0; o < OPS; ++o) {
          float l2 = lg[o] - logZ;
          ent -= expf(l2) * l2;
        }
        out[E - 1]     = (float)act;
        out[2 * E - 1] = lp;
        out[3 * E - 1] = ent;
      }
    }
  }
}

// ===========================================================================
extern "C" void kernel_launch(void* const* d_in, const int* in_sizes, int n_in,
                              void* d_out, int out_size, void* d_ws, size_t ws_size,
                              hipStream_t stream) {
  (void)out_size; (void)ws_size;
  float* out = (float*)d_out;
  float* ws  = (float*)d_ws;

  (void)hipGetLastError();

  static const long long expect[16] = {
      1, 1024, 1024, 1048576, 1048576, 2048, 2048,
      1048576, 1048576, 2048, 2048, 6144,
      29360128, 57344, 688128, 1344 };
  int bad = -1;
  if (n_in != 16) bad = 99;
  else {
    for (int i = 0; i < 16; ++i)
      if ((long long)in_sizes[i] != expect[i]) { bad = i; break; }
  }

  k_init<<<12, 256, 0, stream>>>((u64*)(ws + 16));
  if (bad >= 0) {
    k_diag<<<1, 64, 0, stream>>>(out, 80000.0f + (float)bad);
    return;
  }

  policy_persist<<<NWG, NT, 0, stream>>>(
      d_in[0],
      (const float*)d_in[1],  (const float*)d_in[2],
      (const float*)d_in[3],  (const float*)d_in[4],
      (const float*)d_in[5],  (const float*)d_in[6],
      (const float*)d_in[7],  (const float*)d_in[8],
      (const float*)d_in[9],  (const float*)d_in[10],
      (const float*)d_in[11], (const float*)d_in[12],
      (const float*)d_in[13], (const float*)d_in[14],
      (const float*)d_in[15],
      out, ws);

  hipError_t e = hipGetLastError();
  if (e != hipSuccess) {
    k_diag<<<1, 64, 0, stream>>>(out, 90000.0f + (float)(int)e);
  }
}

// Round 14
// 1082.422 us; speedup vs baseline: 2.8609x; 1.0084x over previous
//
#include <hip/hip_runtime.h>
#include <math.h>

#define H    512
#define OPS  12
#define E    112
#define NWG  128
#define NT   256

typedef unsigned long long u64;
typedef unsigned int u32x4 __attribute__((ext_vector_type(4)));

// ws layout: 16-float header | 3072 tagged u64
#define TW_HB0   0                    // [2][512] h0n
#define TW_HB1   1024                 // [2][512] h1n
#define TW_HMB   2048                 // [2][512] controller hidden
#define TW_TOTAL 3072

// bank-conflict-killing row rotation for h-vectors: word j lives at SW(j).
// Rotation amount is a multiple of 4 -> float4 groups stay contiguous and
// 16B-aligned; 32-stride readers spread across 8 bank windows (2-way, free).
#define SW(j) (((j) & ~31) | (((j) + ((((j) >> 5) & 7) << 2)) & 31))

__device__ __forceinline__ float sigf(float x) { return 1.f / (1.f + expf(-x)); }

// JAX threefry2x32, key = PRNGKey(42) = (0,42), 20 rounds
__device__ __forceinline__ void threefry_42(unsigned x0, unsigned x1,
                                            unsigned& o0, unsigned& o1) {
  const unsigned k0 = 0u, k1 = 42u;
  const unsigned k2 = k0 ^ k1 ^ 0x1BD11BDAu;
  x0 += k0; x1 += k1;
#define TF_R(rot) { x0 += x1; x1 = (x1 << rot) | (x1 >> (32 - rot)); x1 ^= x0; }
  TF_R(13) TF_R(15) TF_R(26) TF_R(6)
  x0 += k1; x1 += k2 + 1u;
  TF_R(17) TF_R(29) TF_R(16) TF_R(24)
  x0 += k2; x1 += k0 + 2u;
  TF_R(13) TF_R(15) TF_R(26) TF_R(6)
  x0 += k0; x1 += k1 + 3u;
  TF_R(17) TF_R(29) TF_R(16) TF_R(24)
  x0 += k1; x1 += k2 + 4u;
  TF_R(13) TF_R(15) TF_R(26) TF_R(6)
  x0 += k2; x1 += k0 + 5u;
#undef TF_R
  o0 = x0; o1 = x1;
}

__device__ __forceinline__ float bits_to_gumbel(unsigned bits) {
  unsigned fb = (bits >> 9) | 0x3f800000u;
  float u = __uint_as_float(fb) - 1.0f;
  u = u + 1.17549435e-38f;
  u = fmaxf(1.17549435e-38f, u);
  return -logf(-logf(u));
}

__device__ __forceinline__ float decode_temp(const void* temp_p) {
  float tf = *(const float*)temp_p;
  float a = fabsf(tf);
  if (a > 1e-6f && a < 1e6f) return tf;
  int ti = *(const int*)temp_p;
  if (ti != 0 && ti > -1000000 && ti < 1000000) return (float)ti;
  double td = *(const double*)temp_p;
  double ad = fabs(td);
  if (ad > 1e-6 && ad < 1e6) return (float)td;
  return 1.0f;
}

// MALL-coherent tagged-word transport (tag<<32 | float bits)
__device__ __forceinline__ void tag_store(u64* p, unsigned tag, float f) {
  u64 v = ((u64)tag << 32) | (u64)__float_as_uint(f);
  __hip_atomic_store(p, v, __ATOMIC_RELAXED, __HIP_MEMORY_SCOPE_SYSTEM);
}
// poll TWO adjacent tagged words with ONE 16B cache-bypassing load
__device__ __forceinline__ void tag_poll2(const u64* p, unsigned tag,
                                          float& f0, float& f1) {
  u32x4 v;
  for (;;) {
    asm volatile("global_load_dwordx4 %0, %1, off sc0 sc1\n\t"
                 "s_waitcnt vmcnt(0)"
                 : "=&v"(v) : "v"(p) : "memory");
    if (v.y == tag && v.w == tag) break;
    __builtin_amdgcn_s_sleep(1);
  }
  f0 = __uint_as_float(v.x);
  f1 = __uint_as_float(v.z);
}

__global__ void k_init(u64* tw) {
  int t = blockIdx.x * blockDim.x + threadIdx.x;
  if (t < TW_TOTAL) tw[t] = 0ull;
}
__global__ void k_diag(float* out, float v) {
  if (threadIdx.x == 0 && blockIdx.x == 0) out[0] = v;
}

// ===========================================================================
__global__ void __launch_bounds__(NT)
policy_persist(const void* temp_p,
               const float* __restrict__ h0_in, const float* __restrict__ c0_in,
               const float* __restrict__ Wih0,  const float* __restrict__ Whh0,
               const float* __restrict__ bih0,  const float* __restrict__ bhh0,
               const float* __restrict__ Wih1,  const float* __restrict__ Whh1,
               const float* __restrict__ bih1,  const float* __restrict__ bhh1,
               const float* __restrict__ emb,   const float* __restrict__ cW1,
               const float* __restrict__ cb1,   const float* __restrict__ cW2,
               const float* __restrict__ cb2,
               float* __restrict__ out, float* ws) {
  __shared__ __align__(16) float h0full[H], shp1[H], hm[H];
  __shared__ float g0pre[16], g1bpre[16], g1loc[16];
  __shared__ float ewloc[12 * 16], b0loc[16], b1loc[16];
  __shared__ float gum[E * OPS];
  __shared__ float w1s[512 * 5];          // W1[i] 4-col slice, stride-5
  __shared__ float w2s[512 * 13];         // W2[i], stride-13 (row-copied)
  __shared__ float c0loc[4], c1loc[4];
  __shared__ float spart[4][4];

  const int tid = threadIdx.x;
  const int bid = blockIdx.x;
  const int j0  = bid * 4;                       // owned h-columns
  const int cb  = (bid & 7) * 16 + (bid >> 3);   // XCD-grouped HM col-block
  const float invt = 1.f / decode_temp(temp_p);

  u64* HB0 = (u64*)(ws + 16) + TW_HB0;
  u64* HB1 = (u64*)(ws + 16) + TW_HB1;
  u64* HMB = (u64*)(ws + 16) + TW_HMB;

  // ---------------- setup (all WG-local) -----------------------------------
  for (int p = tid; p < E * OPS; p += NT) {
    unsigned y0, y1;
    threefry_42(0u, (unsigned)p, y0, y1);
    gum[p] = bits_to_gumbel(y0 ^ y1);
  }
  for (int j = tid; j < H; j += NT) {
    h0full[SW(j)] = h0_in[j];
    shp1[SW(j)]   = h0_in[H + j];
  }
  if (tid < 192) {
    int a = tid / 16, ridx = tid % 16;
    int g = ridx >> 2, dj = ridx & 3;
    int row = g * H + j0 + dj;
    const float* er = emb + a * H;
    const float* wr = Wih0 + (size_t)row * H;
    float acc = 0.f;
    for (int k = 0; k < H; k += 4) {
      float4 e4 = *(const float4*)(er + k);
      float4 w4 = *(const float4*)(wr + k);
      acc += e4.x * w4.x + e4.y * w4.y + e4.z * w4.z + e4.w * w4.w;
    }
    ewloc[tid] = acc;
  }
  if (tid < 16) {
    int g = tid >> 2, dj = tid & 3;
    int row = g * H + j0 + dj;
    b0loc[tid] = bih0[row] + bhh0[row];
    b1loc[tid] = bih1[row] + bhh1[row];
  }
  if (tid < 4) {
    c0loc[tid] = c0_in[j0 + tid];
    c1loc[tid] = c0_in[H + j0 + tid];
  }
  __syncthreads();

  // G-pre(0) combined pass + W1[0] prefetch (round-9 math, swizzled reads)
  {
    int rowidx = tid >> 3, lane = tid & 7;
    int cell = rowidx >> 4, ridx = rowidx & 15;
    int g = ridx >> 2, dj = ridx & 3;
    int row = g * H + j0 + dj;
    const float* wr = (cell ? Whh1 : Whh0) + (size_t)row * H + lane * 64;
    const float* hv = cell ? shp1 : h0full;
    float acc = 0.f;
#pragma unroll
    for (int k = 0; k < 64; k += 4) {
      float4 w4 = *(const float4*)(wr + k);
      float4 h4 = *(const float4*)&hv[SW(lane * 64 + k)];
      acc += w4.x * h4.x + w4.y * h4.y + w4.z * h4.z + w4.w * h4.w;
    }
    acc += __shfl_xor(acc, 1);
    acc += __shfl_xor(acc, 2);
    acc += __shfl_xor(acc, 4);
    if (lane == 0) {
      if (cell == 0) g0pre[ridx] = acc + b0loc[ridx];
      else           g1bpre[ridx] = acc;
    }
    const float* wb = cW1 + (size_t)cb * 4;
    float4 r0 = *(const float4*)(wb + (size_t)tid * H);
    float4 r1 = *(const float4*)(wb + (size_t)(tid + 256) * H);
    int k0 = tid * 5, k1 = (tid + 256) * 5;
    w1s[k0] = r0.x; w1s[k0 + 1] = r0.y; w1s[k0 + 2] = r0.z; w1s[k0 + 3] = r0.w;
    w1s[k1] = r1.x; w1s[k1 + 1] = r1.y; w1s[k1 + 2] = r1.z; w1s[k1 + 3] = r1.w;
  }
  __syncthreads();

#pragma unroll 1
  for (int i = 0; i < E; ++i) {
    const int p = i & 1;
    const unsigned tg = (unsigned)(i + 1);

    // ---- 1: sample step i-1; PW0 + h0n store issued BEFORE logZ/lp/ent ----
    if (i > 0) {
      const int q = (i - 1) & 1;
      int t2 = tid * 2;
      tag_poll2(&HMB[q * 512 + t2], (unsigned)i, hm[t2], hm[t2 + 1]);
      __syncthreads();
      if (tid < 64) {
        float lg[OPS];
#pragma unroll
        for (int o = 0; o < OPS; ++o) lg[o] = 0.f;
#pragma unroll
        for (int jj = 0; jj < 8; ++jj) {
          int j = jj * 64 + tid;
          float hmv = hm[j];
          const float* w2r = &w2s[j * 13];
#pragma unroll
          for (int o = 0; o < OPS; ++o) lg[o] += hmv * w2r[o];
        }
#pragma unroll
        for (int s = 1; s < 64; s <<= 1) {
#pragma unroll
          for (int o = 0; o < OPS; ++o) lg[o] += __shfl_xor(lg[o], s);
        }
#pragma unroll
        for (int o = 0; o < OPS; ++o) lg[o] = (lg[o] + cb2[(i - 1) * OPS + o]) * invt;
        // argmax FIRST (lg identical across lanes after reduce; gum is LDS)
        float best = -1e30f; int act = 0;
#pragma unroll
        for (int o = 0; o < OPS; ++o) {
          float v = lg[o] + gum[(i - 1) * OPS + o];
          if (v > best) { best = v; act = o; }
        }
        // PW0 (lanes 0-3) + h0n tagged store — critical path head
        if (tid < 4) {
          float gi = g0pre[tid]      + ewloc[act * 16 + tid];
          float gf = g0pre[4 + tid]  + ewloc[act * 16 + 4 + tid];
          float gg = g0pre[8 + tid]  + ewloc[act * 16 + 8 + tid];
          float go = g0pre[12 + tid] + ewloc[act * 16 + 12 + tid];
          float cn = sigf(gf) * c0loc[tid] + sigf(gi) * tanhf(gg);
          c0loc[tid] = cn;
          tag_store(&HB0[p * 512 + j0 + tid], tg, sigf(go) * tanhf(cn));
        }
        // lp/ent/out — off the chain, bid 0 only
        if (bid == 0) {
          float mx = lg[0];
#pragma unroll
          for (int o = 1; o < OPS; ++o) mx = fmaxf(mx, lg[o]);
          float se = 0.f;
#pragma unroll
          for (int o = 0; o < OPS; ++o) se += expf(lg[o] - mx);
          float logZ = mx + logf(se);
          if (tid == 0) {
            float lp = lg[act] - logZ;
            float ent = 0.f;
            for (int o = 0; o < OPS; ++o) {
              float l2 = lg[o] - logZ;
              ent -= expf(l2) * l2;
            }
            out[i - 1]         = (float)act;
            out[E + i - 1]     = lp;
            out[2 * E + i - 1] = ent;
          }
        }
      }
      // no barrier: everything above is wave-0-internal
    } else {
      // i == 0: PW0 without embedding contribution
      if (tid < 4) {
        float gi = g0pre[tid];
        float gf = g0pre[4 + tid];
        float gg = g0pre[8 + tid];
        float go = g0pre[12 + tid];
        float cn = sigf(gf) * c0loc[tid] + sigf(gi) * tanhf(gg);
        c0loc[tid] = cn;
        tag_store(&HB0[p * 512 + j0 + tid], tg, sigf(go) * tanhf(cn));
      }
    }

    // ---- 3: poll full h0n (swizzled LDS commit) ---------------------------
    {
      int t2 = tid * 2;
      int sw = SW(t2);                   // pair stays adjacent (t2 even)
      tag_poll2(&HB0[p * 512 + t2], tg, h0full[sw], h0full[sw + 1]);
    }
    __syncthreads();

    // ---- 4: G1 = Wih1@h0n + G1Bpre + B1 (own 16 rows, 16 lanes/row) -------
    {
      int ridx = tid >> 4, lane = tid & 15;
      int g = ridx >> 2, dj = ridx & 3;
      int row = g * H + j0 + dj;
      const float* wr = Wih1 + (size_t)row * H + lane * 32;
      float acc = 0.f;
#pragma unroll
      for (int k = 0; k < 32; k += 4) {
        float4 w4 = *(const float4*)(wr + k);
        float4 h4 = *(const float4*)&h0full[SW(lane * 32 + k)];
        acc += w4.x * h4.x + w4.y * h4.y + w4.z * h4.z + w4.w * h4.w;
      }
      acc += __shfl_xor(acc, 1);
      acc += __shfl_xor(acc, 2);
      acc += __shfl_xor(acc, 4);
      acc += __shfl_xor(acc, 8);
      if (lane == 0) g1loc[ridx] = acc + g1bpre[ridx] + b1loc[ridx];
    }
    __syncthreads();

    // ---- 5: PW1 (own 4 cols) -> tagged h1n store --------------------------
    if (tid < 4) {
      float gi = g1loc[tid];
      float gf = g1loc[4 + tid];
      float gg = g1loc[8 + tid];
      float go = g1loc[12 + tid];
      float cn = sigf(gf) * c1loc[tid] + sigf(gi) * tanhf(gg);
      c1loc[tid] = cn;
      tag_store(&HB1[p * 512 + j0 + tid], tg, sigf(go) * tanhf(cn));
    }

    // ---- 6: shadow-1: issue W1[i+1] loads; G0pre(i+1); W2[i] -> w2s -------
    float4 v0, v1;
    if (i + 1 < E) {
      const float* wb = cW1 + (size_t)(i + 1) * H * H + (size_t)cb * 4;
      v0 = *(const float4*)(wb + (size_t)tid * H);
      v1 = *(const float4*)(wb + (size_t)(tid + 256) * H);
    }
    if (tid < 128) {
      int ridx = tid >> 3, lane = tid & 7;
      int g = ridx >> 2, dj = ridx & 3;
      int row = g * H + j0 + dj;
      const float* wr = Whh0 + (size_t)row * H + lane * 64;
      float acc = 0.f;
#pragma unroll
      for (int k = 0; k < 64; k += 4) {
        float4 w4 = *(const float4*)(wr + k);
        float4 h4 = *(const float4*)&h0full[SW(lane * 64 + k)];
        acc += w4.x * h4.x + w4.y * h4.y + w4.z * h4.z + w4.w * h4.w;
      }
      acc += __shfl_xor(acc, 1);
      acc += __shfl_xor(acc, 2);
      acc += __shfl_xor(acc, 4);
      if (lane == 0) g0pre[ridx] = acc + b0loc[ridx];
    }
    {
      // W2[i] staging: thread t copies rows 2t, 2t+1 (12 floats each).
      // LDS writes at 13*row are 2-way bank-aliased (free); values and the
      // w2s layout are identical to before — only the write pattern changed.
      const float* wsrc = cW2 + (size_t)i * H * OPS;
#pragma unroll
      for (int rr = 0; rr < 2; ++rr) {
        int r = tid * 2 + rr;
        const float* s = wsrc + r * 12;
        float4 a = *(const float4*)(s);
        float4 b = *(const float4*)(s + 4);
        float4 c = *(const float4*)(s + 8);
        float* d = &w2s[r * 13];
        d[0] = a.x; d[1] = a.y; d[2]  = a.z; d[3]  = a.w;
        d[4] = b.x; d[5] = b.y; d[6]  = b.z; d[7]  = b.w;
        d[8] = c.x; d[9] = c.y; d[10] = c.z; d[11] = c.w;
      }
    }

    // ---- 7: poll full h1n (swizzled LDS commit) ---------------------------
    {
      int t2 = tid * 2;
      int sw = SW(t2);
      tag_poll2(&HB1[p * 512 + t2], tg, shp1[sw], shp1[sw + 1]);
    }
    __syncthreads();

    // ---- 8: phase C: HM own 4 cols from LDS W1 ----------------------------
    {
      int wv = tid >> 6, ln = tid & 63;
      int jl = ln & 3, ks = ln >> 2;
      int kbase = wv * 128 + ks * 8;
      float acc = 0.f;
#pragma unroll
      for (int t = 0; t < 8; ++t) {
        int k = kbase + t;
        acc += shp1[SW(k)] * w1s[k * 5 + jl];
      }
      acc += __shfl_xor(acc, 4);
      acc += __shfl_xor(acc, 8);
      acc += __shfl_xor(acc, 16);
      acc += __shfl_xor(acc, 32);
      if (ln < 4) spart[wv][ln] = acc;
    }
    __syncthreads();
    if (tid < 4) {
      float s = spart[0][tid] + spart[1][tid] + spart[2][tid] + spart[3][tid];
      s += cb1[(size_t)i * H + cb * 4 + tid];
      tag_store(&HMB[p * 512 + cb * 4 + tid], tg, fmaxf(s, 0.f));
    }

    // ---- 9: shadow-2: G1Bpre(i+1); commit W1[i+1] -> w1s ------------------
    if (i + 1 < E) {
      if (tid < 128) {
        int ridx = tid >> 3, lane = tid & 7;
        int g = ridx >> 2, dj = ridx & 3;
        int row = g * H + j0 + dj;
        const float* wr = Whh1 + (size_t)row * H + lane * 64;
        float acc = 0.f;
#pragma unroll
        for (int k = 0; k < 64; k += 4) {
          float4 w4 = *(const float4*)(wr + k);
          float4 h4 = *(const float4*)&shp1[SW(lane * 64 + k)];
          acc += w4.x * h4.x + w4.y * h4.y + w4.z * h4.z + w4.w * h4.w;
        }
        acc += __shfl_xor(acc, 1);
        acc += __shfl_xor(acc, 2);
        acc += __shfl_xor(acc, 4);
        if (lane == 0) g1bpre[ridx] = acc;
      }
      int k0 = tid * 5, k1 = (tid + 256) * 5;
      w1s[k0] = v0.x; w1s[k0 + 1] = v0.y; w1s[k0 + 2] = v0.z; w1s[k0 + 3] = v0.w;
      w1s[k1] = v1.x; w1s[k1 + 1] = v1.y; w1s[k1 + 2] = v1.z; w1s[k1 + 3] = v1.w;
    }
    // no loop-end barrier: next step's HM/h0n poll barriers cover all
    // cross-wave LDS dependences (w1s/w2s/g0pre/g1bpre vs their readers).
  }

  // ---- final sampling (step E-1); w2s = W2[E-1] ---------------------------
  if (bid == 0) {
    const int q = (E - 1) & 1;
    int t2 = tid * 2;
    tag_poll2(&HMB[q * 512 + t2], (unsigned)E, hm[t2], hm[t2 + 1]);
    __syncthreads();
    if (tid < 64) {
      float lg[OPS];
#pragma unroll
      for (int o = 0; o < OPS; ++o) lg[o] = 0.f;
#pragma unroll
      for (int jj = 0; jj < 8; ++jj) {
        int j = jj * 64 + tid;
        float hmv = hm[j];
        const float* w2r = &w2s[j * 13];
#pragma unroll
        for (int o = 0; o < OPS; ++o) lg[o] += hmv * w2r[o];
      }
#pragma unroll
      for (int s = 1; s < 64; s <<= 1) {
#pragma unroll
        for (int o = 0; o < OPS; ++o) lg[o] += __shfl_xor(lg[o], s);
      }
#pragma unroll
      for (int o = 0; o < OPS; ++o) lg[o] = (lg[o] + cb2[(E - 1) * OPS + o]) * invt;
      float mx = lg[0];
#pragma unroll
      for (int o = 1; o < OPS; ++o) mx = fmaxf(mx, lg[o]);
      float se = 0.f;
#pragma unroll
      for (int o = 0; o < OPS; ++o) se += expf(lg[o] - mx);
      float logZ = mx + logf(se);
      float best = -1e30f; int act = 0;
#pragma unroll
      for (int o = 0; o < OPS; ++o) {
        float v = lg[o] + gum[(E - 1) * OPS + o];
        if (v > best) { best = v; act = o; }
      }
      if (tid == 0) {
        float lp = lg[act] - logZ;
        float ent = 0.f;
        for (int o = 0; o < OPS; ++o) {
          float l2 = lg[o] - logZ;
          ent -= expf(l2) * l2;
        }
        out[E - 1]     = (float)act;
        out[2 * E - 1] = lp;
        out[3 * E - 1] = ent;
      }
    }
  }
}

// ===========================================================================
extern "C" void kernel_launch(void* const* d_in, const int* in_sizes, int n_in,
                              void* d_out, int out_size, void* d_ws, size_t ws_size,
                              hipStream_t stream) {
  (void)out_size; (void)ws_size;
  float* out = (float*)d_out;
  float* ws  = (float*)d_ws;

  (void)hipGetLastError();

  static const long long expect[16] = {
      1, 1024, 1024, 1048576, 1048576, 2048, 2048,
      1048576, 1048576, 2048, 2048, 6144,
      29360128, 57344, 688128, 1344 };
  int bad = -1;
  if (n_in != 16) bad = 99;
  else {
    for (int i = 0; i < 16; ++i)
      if ((long long)in_sizes[i] != expect[i]) { bad = i; break; }
  }

  k_init<<<12, 256, 0, stream>>>((u64*)(ws + 16));
  if (bad >= 0) {
    k_diag<<<1, 64, 0, stream>>>(out, 80000.0f + (float)bad);
    return;
  }

  policy_persist<<<NWG, NT, 0, stream>>>(
      d_in[0],
      (const float*)d_in[1],  (const float*)d_in[2],
      (const float*)d_in[3],  (const float*)d_in[4],
      (const float*)d_in[5],  (const float*)d_in[6],
      (const float*)d_in[7],  (const float*)d_in[8],
      (const float*)d_in[9],  (const float*)d_in[10],
      (const float*)d_in[11], (const float*)d_in[12],
      (const float*)d_in[13], (const float*)d_in[14],
      (const float*)d_in[15],
      out, ws);

  hipError_t e = hipGetLastError();
  if (e != hipSuccess) {
    k_diag<<<1, 64, 0, stream>>>(out, 90000.0f + (float)(int)e);
  }
}